// Round 12
// baseline (209.499 us; speedup 1.0000x reference)
//
#include <hip/hip_runtime.h>
#include <math.h>

#define N_NODES 100000
#define E_EDGES 1600000
#define EA (E_EDGES + N_NODES)   // with self loops
#define NEG_SLOPE 0.2f
#define LG_BUCKET 7
#define BUCKET (1 << LG_BUCKET)            // 128-node dst buckets
#define NB ((N_NODES + BUCKET - 1) >> LG_BUCKET)   // 782
#define LG_SLOTS 12
#define SLOTS (1 << LG_SLOTS)    // per-bucket slack region (mean fill ~2174)
#define CH 2048                  // edges per block in partition pass
#define NPB ((EA + CH - 1) / CH) // 831 partition blocks
#define SRC_BITS 17
#define SRC_MASK ((1u << SRC_BITS) - 1)
#define CAP 96                   // per-node LDS softmax cache for agg2 (max deg ~40)

typedef _Float16 f16;
typedef _Float16 half2v __attribute__((ext_vector_type(2)));

__device__ __forceinline__ float leaky(float e) { return e >= 0.f ? e : NEG_SLOPE * e; }
__device__ __forceinline__ unsigned h2u(half2v h) { return __builtin_bit_cast(unsigned, h); }
__device__ __forceinline__ half2v u2h(unsigned u) { return __builtin_bit_cast(half2v, u); }
__device__ __forceinline__ half2v cvtpk(float a, float b) {
    return __builtin_bit_cast(half2v, __builtin_amdgcn_cvt_pkrtz(a, b));
}

// ---------------- CSR build: slack-bucket partition, in-place scatter ----------------

// partition edges into per-bucket slack regions as packed u32 (localDst<<17 | src)
__global__ __launch_bounds__(256) void partition_kernel(const int* __restrict__ src,
                                                        const int* __restrict__ dst,
                                                        int* __restrict__ bcnt,
                                                        unsigned* __restrict__ edges) {
    __shared__ int hist[NB];
    __shared__ int base[NB];
    int t = threadIdx.x;
    for (int i = t; i < NB; i += 256) hist[i] = 0;
    __syncthreads();
    int e0 = blockIdx.x * CH;
    int e1 = e0 + CH < EA ? e0 + CH : EA;
    for (int e = e0 + t; e < e1; e += 256) {
        int d = (e < E_EDGES) ? dst[e] : (e - E_EDGES);
        atomicAdd(&hist[d >> LG_BUCKET], 1);
    }
    __syncthreads();
    for (int i = t; i < NB; i += 256) {
        int h = hist[i];
        base[i] = h ? atomicAdd(&bcnt[i], h) : 0;
        hist[i] = 0;   // reuse as local cursor
    }
    __syncthreads();
    for (int e = e0 + t; e < e1; e += 256) {
        int s, d;
        if (e < E_EDGES) { s = src[e]; d = dst[e]; } else { s = e - E_EDGES; d = s; }
        int b = d >> LG_BUCKET;
        int r = base[b] + atomicAdd(&hist[b], 1);
        if (r < SLOTS)   // overflow guard (mean fill 2174, ~40 sigma margin)
            edges[(b << LG_SLOTS) + r] = ((unsigned)(d & (BUCKET - 1)) << SRC_BITS) | (unsigned)s;
    }
}

// per-bucket local scatter (in-place via LDS staging); emits rowSD = {start, deg}
__global__ __launch_bounds__(256) void bucket_scatter(unsigned* __restrict__ edges,
                                                      const int* __restrict__ bcnt,
                                                      int2* __restrict__ rowSD) {
    __shared__ unsigned stage[SLOTS];   // 16 KB
    __shared__ int hist[256];
    __shared__ int sc[256];
    int b = blockIdx.x;
    int t = threadIdx.x;
    int node0 = b << LG_BUCKET;
    int cnt = bcnt[b]; if (cnt > SLOTS) cnt = SLOTS;
    int baseg = b << LG_SLOTS;
    hist[t] = 0;
    __syncthreads();
    for (int i = t; i < cnt; i += 256) {
        unsigned p = edges[baseg + i];
        stage[i] = p;
        atomicAdd(&hist[p >> SRC_BITS], 1);   // local dst < BUCKET <= 256
    }
    __syncthreads();
    int v = hist[t];
    sc[t] = v;
    __syncthreads();
    for (int off = 1; off < 256; off <<= 1) {
        int x = (t >= off) ? sc[t - off] : 0;
        __syncthreads();
        sc[t] += x;
        __syncthreads();
    }
    int excl = sc[t] - v;
    if (t < BUCKET && node0 + t < N_NODES) rowSD[node0 + t] = make_int2(baseg + excl, v);
    hist[t] = excl;   // reuse as cursor
    __syncthreads();
    for (int i = t; i < cnt; i += 256) {
        unsigned p = stage[i];
        int r = atomicAdd(&hist[p >> SRC_BITS], 1);
        edges[baseg + r] = p & SRC_MASK;   // in-place: now plain src index
    }
}

// ---------------- Layer 1: linear + logits (16 rows/block) ----------------

__global__ __launch_bounds__(256) void lin1_kernel(
        const float* __restrict__ x, const float* __restrict__ W1,
        const float* __restrict__ a1s, const float* __restrict__ a1d,
        f16* __restrict__ h1, float* __restrict__ as1, float* __restrict__ ad1) {
    __shared__ float Wl[64 * 64];
    __shared__ float xs[16 * 64];
    int tid = threadIdx.x;
    int r0 = blockIdx.x * 16;
    const float4* W4 = (const float4*)W1;
    float4* Wl4 = (float4*)Wl;
    #pragma unroll
    for (int i = 0; i < 4; i++) Wl4[tid + i * 256] = W4[tid + i * 256];
    ((float4*)xs)[tid] = ((const float4*)(x + (size_t)r0 * 64))[tid];
    __syncthreads();
    int c = tid & 63, tg = tid >> 6;
    float acc0 = 0.f, acc1 = 0.f, acc2 = 0.f, acc3 = 0.f;
    #pragma unroll
    for (int k = 0; k < 64; k++) {
        float w = Wl[k * 64 + c];
        acc0 += xs[(tg * 4 + 0) * 64 + k] * w;
        acc1 += xs[(tg * 4 + 1) * 64 + k] * w;
        acc2 += xs[(tg * 4 + 2) * 64 + k] * w;
        acc3 += xs[(tg * 4 + 3) * 64 + k] * w;
    }
    int r = r0 + tg * 4;
    h1[(size_t)(r + 0) * 64 + c] = (f16)acc0;
    h1[(size_t)(r + 1) * 64 + c] = (f16)acc1;
    h1[(size_t)(r + 2) * 64 + c] = (f16)acc2;
    h1[(size_t)(r + 3) * 64 + c] = (f16)acc3;
    float s_c = a1s[c], d_c = a1d[c];
    float vs0 = acc0 * s_c, vd0 = acc0 * d_c;
    float vs1 = acc1 * s_c, vd1 = acc1 * d_c;
    float vs2 = acc2 * s_c, vd2 = acc2 * d_c;
    float vs3 = acc3 * s_c, vd3 = acc3 * d_c;
    #pragma unroll
    for (int off = 16; off > 0; off >>= 1) {
        vs0 += __shfl_xor(vs0, off); vd0 += __shfl_xor(vd0, off);
        vs1 += __shfl_xor(vs1, off); vd1 += __shfl_xor(vd1, off);
        vs2 += __shfl_xor(vs2, off); vd2 += __shfl_xor(vd2, off);
        vs3 += __shfl_xor(vs3, off); vd3 += __shfl_xor(vd3, off);
    }
    if ((c & 31) == 0) {
        int h = c >> 5;
        as1[(r + 0) * 2 + h] = vs0; ad1[(r + 0) * 2 + h] = vd0;
        as1[(r + 1) * 2 + h] = vs1; ad1[(r + 1) * 2 + h] = vd1;
        as1[(r + 2) * 2 + h] = vs2; ad1[(r + 2) * 2 + h] = vd2;
        as1[(r + 3) * 2 + h] = vs3; ad1[(r + 3) * 2 + h] = vd3;
    }
}

// ---------------- Layer 1 aggregation + fused layer-2 linear (R11-proven + unroll-8) ----------------
// half-wave per node; lane l covers feature pair (2l,2l+1), head hh = l>>4.
// Single pass: per 32-edge chunk each lane computes its edge's p (both heads,
// cvt_pkrtz-packed); inner loop shfl-broadcasts s and p; head via v_perm splat;
// accumulate with v_pk_fma_f16. 8-wide unroll tier for more gathers in flight.

__global__ __launch_bounds__(256) void agg1_kernel(
        const int2* __restrict__ rowSD, const int* __restrict__ srcs,
        const f16* __restrict__ h1, const float* __restrict__ as1,
        const float* __restrict__ ad1, const float* __restrict__ b1,
        const float* __restrict__ W2, const float* __restrict__ a2s,
        const float* __restrict__ a2d,
        f16* __restrict__ h2, float* __restrict__ as2, float* __restrict__ ad2) {
    __shared__ float rowb[8][68];
    __shared__ float W2l[64 * 32];
    int tid = threadIdx.x;
    for (int i = tid; i < 2048; i += 256) W2l[i] = W2[i];
    int hwid = tid >> 5;        // 0..7 half-wave id
    int l = tid & 31;           // lane in half
    int hh = l >> 4;            // head for this lane's feature pair
    int v = blockIdx.x * 8 + hwid;
    int2 sd = rowSD[v];
    int start = sd.x, deg = sd.y;
    float2 adv = ((const float2*)ad1)[v];
    const float2* as1v2 = (const float2*)as1;
    const half2v* h1v = (const half2v*)h1;
    unsigned psel = hh ? 0x03020302u : 0x01000100u;   // splat hi16 : lo16
    half2v accA = {}, accB = {};
    float z0 = 0.f, z1 = 0.f;
    for (int c = 0; c < deg; c += 32) {
        int cnt = deg - c; if (cnt > 32) cnt = 32;
        int sreg = 0, pki = 0;
        if (c + l < deg) {
            sreg = srcs[start + c + l];
            float2 a = as1v2[sreg];
            float p0 = __expf(leaky(a.x + adv.x));
            float p1 = __expf(leaky(a.y + adv.y));
            half2v pk = cvtpk(p0, p1);
            z0 += (float)pk.x;   // z from rounded p: cancels RTZ bias
            z1 += (float)pk.y;
            pki = (int)h2u(pk);
        }
        int j = 0;
        for (; j + 7 < cnt; j += 8) {
            int s0 = __shfl(sreg, j, 32),     s1 = __shfl(sreg, j + 1, 32);
            int s2 = __shfl(sreg, j + 2, 32), s3 = __shfl(sreg, j + 3, 32);
            int s4 = __shfl(sreg, j + 4, 32), s5 = __shfl(sreg, j + 5, 32);
            int s6 = __shfl(sreg, j + 6, 32), s7 = __shfl(sreg, j + 7, 32);
            unsigned u0 = (unsigned)__shfl(pki, j, 32);
            unsigned u1 = (unsigned)__shfl(pki, j + 1, 32);
            unsigned u2 = (unsigned)__shfl(pki, j + 2, 32);
            unsigned u3 = (unsigned)__shfl(pki, j + 3, 32);
            unsigned u4 = (unsigned)__shfl(pki, j + 4, 32);
            unsigned u5 = (unsigned)__shfl(pki, j + 5, 32);
            unsigned u6 = (unsigned)__shfl(pki, j + 6, 32);
            unsigned u7 = (unsigned)__shfl(pki, j + 7, 32);
            half2v g0 = h1v[s0 * 32 + l];
            half2v g1 = h1v[s1 * 32 + l];
            half2v g2 = h1v[s2 * 32 + l];
            half2v g3 = h1v[s3 * 32 + l];
            half2v g4 = h1v[s4 * 32 + l];
            half2v g5 = h1v[s5 * 32 + l];
            half2v g6 = h1v[s6 * 32 + l];
            half2v g7 = h1v[s7 * 32 + l];
            accA += u2h(__builtin_amdgcn_perm(u0, u0, psel)) * g0;
            accA += u2h(__builtin_amdgcn_perm(u1, u1, psel)) * g1;
            accB += u2h(__builtin_amdgcn_perm(u2, u2, psel)) * g2;
            accB += u2h(__builtin_amdgcn_perm(u3, u3, psel)) * g3;
            accA += u2h(__builtin_amdgcn_perm(u4, u4, psel)) * g4;
            accA += u2h(__builtin_amdgcn_perm(u5, u5, psel)) * g5;
            accB += u2h(__builtin_amdgcn_perm(u6, u6, psel)) * g6;
            accB += u2h(__builtin_amdgcn_perm(u7, u7, psel)) * g7;
        }
        for (; j + 3 < cnt; j += 4) {
            int s0 = __shfl(sreg, j, 32),     s1 = __shfl(sreg, j + 1, 32);
            int s2 = __shfl(sreg, j + 2, 32), s3 = __shfl(sreg, j + 3, 32);
            unsigned u0 = (unsigned)__shfl(pki, j, 32);
            unsigned u1 = (unsigned)__shfl(pki, j + 1, 32);
            unsigned u2 = (unsigned)__shfl(pki, j + 2, 32);
            unsigned u3 = (unsigned)__shfl(pki, j + 3, 32);
            half2v g0 = h1v[s0 * 32 + l];
            half2v g1 = h1v[s1 * 32 + l];
            half2v g2 = h1v[s2 * 32 + l];
            half2v g3 = h1v[s3 * 32 + l];
            accA += u2h(__builtin_amdgcn_perm(u0, u0, psel)) * g0;
            accA += u2h(__builtin_amdgcn_perm(u1, u1, psel)) * g1;
            accB += u2h(__builtin_amdgcn_perm(u2, u2, psel)) * g2;
            accB += u2h(__builtin_amdgcn_perm(u3, u3, psel)) * g3;
        }
        for (; j < cnt; j++) {
            int s0 = __shfl(sreg, j, 32);
            unsigned u0 = (unsigned)__shfl(pki, j, 32);
            half2v g0 = h1v[s0 * 32 + l];
            accA += u2h(__builtin_amdgcn_perm(u0, u0, psel)) * g0;
        }
    }
    // z reduce across the 32-lane half
    #pragma unroll
    for (int off = 16; off > 0; off >>= 1) {
        z0 += __shfl_xor(z0, off);
        z1 += __shfl_xor(z1, off);
    }
    // epilogue: elu(out1) -> LDS row; fused lin2
    float rz = 1.f / (hh ? z1 : z0);
    half2v accT = accA + accB;
    float o0 = (float)accT.x * rz + b1[2 * l];
    float o1 = (float)accT.y * rz + b1[2 * l + 1];
    o0 = o0 > 0.f ? o0 : __expf(o0) - 1.f;
    o1 = o1 > 0.f ? o1 : __expf(o1) - 1.f;
    rowb[hwid][2 * l] = o0;
    rowb[hwid][2 * l + 1] = o1;
    __syncthreads();   // covers W2l staging (and rowb, though same-wave)
    float hc = 0.f;
    #pragma unroll 8
    for (int k = 0; k < 64; k++) hc += rowb[hwid][k] * W2l[k * 32 + l];
    h2[(size_t)v * 32 + l] = (f16)hc;
    float vs = hc * a2s[l], vd = hc * a2d[l];
    #pragma unroll
    for (int off = 16; off > 0; off >>= 1) { vs += __shfl_xor(vs, off); vd += __shfl_xor(vd, off); }
    if (l == 0) { as2[v] = vs; ad2[v] = vd; }
}

// ---------------- Layer 2: aggregation (R8-proven version, verbatim) ----------------

__global__ __launch_bounds__(256) void agg2_kernel(
        const int2* __restrict__ rowSD, const int* __restrict__ srcs,
        const f16* __restrict__ h2, const float* __restrict__ as2,
        const float* __restrict__ ad2, const float* __restrict__ b2,
        float* __restrict__ out) {
    __shared__ float pbuf2[4][CAP];
    int wid = threadIdx.x >> 6;
    int v = blockIdx.x * 4 + wid;
    int lane = threadIdx.x & 63;
    int q = lane >> 4, f = lane & 15;
    int2 sd = rowSD[v];
    int start = sd.x, deg = sd.y;
    float adv = ad2[v];
    const half2v* h2v = (const half2v*)h2;
    float a0 = 0.f, a1 = 0.f, b0 = 0.f, b1v = 0.f;
    float z = 0.f;
    if (deg <= CAP) {
        for (int idx = lane; idx < deg; idx += 64) {
            int s = srcs[start + idx];
            float p = __expf(leaky(as2[s] + adv));
            pbuf2[wid][idx] = p;
            z += p;
        }
        #pragma unroll
        for (int off = 32; off > 0; off >>= 1) z += __shfl_xor(z, off);
        int idx = q;
        for (; idx + 4 < deg; idx += 8) {
            int s0 = srcs[start + idx];
            int s1 = srcs[start + idx + 4];
            float p0 = pbuf2[wid][idx];
            float p1 = pbuf2[wid][idx + 4];
            half2v g0 = h2v[(size_t)s0 * 16 + f];
            half2v g1 = h2v[(size_t)s1 * 16 + f];
            a0 += p0 * (float)g0.x; a1 += p0 * (float)g0.y;
            b0 += p1 * (float)g1.x; b1v += p1 * (float)g1.y;
        }
        if (idx < deg) {
            int s0 = srcs[start + idx];
            float p0 = pbuf2[wid][idx];
            half2v g0 = h2v[(size_t)s0 * 16 + f];
            a0 += p0 * (float)g0.x; a1 += p0 * (float)g0.y;
        }
    } else {
        float m = -1e30f;
        for (int idx = lane; idx < deg; idx += 64)
            m = fmaxf(m, leaky(as2[srcs[start + idx]] + adv));
        #pragma unroll
        for (int off = 32; off > 0; off >>= 1) m = fmaxf(m, __shfl_xor(m, off));
        for (int idx = lane; idx < deg; idx += 64)
            z += __expf(leaky(as2[srcs[start + idx]] + adv) - m);
        #pragma unroll
        for (int off = 32; off > 0; off >>= 1) z += __shfl_xor(z, off);
        for (int idx = q; idx < deg; idx += 4) {
            int s0 = srcs[start + idx];
            float p0 = __expf(leaky(as2[s0] + adv) - m);
            half2v g0 = h2v[(size_t)s0 * 16 + f];
            a0 += p0 * (float)g0.x; a1 += p0 * (float)g0.y;
        }
    }
    a0 += b0; a1 += b1v;
    a0 += __shfl_xor(a0, 16); a1 += __shfl_xor(a1, 16);
    a0 += __shfl_xor(a0, 32); a1 += __shfl_xor(a1, 32);
    if (lane < 16) {
        float rz = 1.f / z;
        float2 r;
        r.x = a0 * rz + b2[2 * f];
        r.y = a1 * rz + b2[2 * f + 1];
        ((float2*)out)[(size_t)v * 16 + f] = r;
    }
}

// ---------------- launch ----------------

extern "C" void kernel_launch(void* const* d_in, const int* in_sizes, int n_in,
                              void* d_out, int out_size, void* d_ws, size_t ws_size,
                              hipStream_t stream) {
    const float* x    = (const float*)d_in[0];
    const int*   ei   = (const int*)d_in[1];
    const float* W1   = (const float*)d_in[2];
    const float* a1s  = (const float*)d_in[3];
    const float* a1d  = (const float*)d_in[4];
    const float* b1   = (const float*)d_in[5];
    const float* W2   = (const float*)d_in[6];
    const float* a2s  = (const float*)d_in[7];
    const float* a2d  = (const float*)d_in[8];
    const float* b2   = (const float*)d_in[9];
    const int* src = ei;
    const int* dst = ei + E_EDGES;
    float* out = (float*)d_out;

    // workspace layout (4-byte words, 64-word aligned regions) — total ~35.2 MB (proven)
    size_t o = 0;
    int2* rowSD     = (int2*)((int*)d_ws + o);     o += ((2 * N_NODES + 63) / 64) * 64;
    int* bcnt       = (int*)d_ws + o;              o += ((NB + 63) / 64) * 64;
    unsigned* edges = (unsigned*)((int*)d_ws + o); o += (size_t)NB * SLOTS;   // packed, then in-place srcs
    f16* h1         = (f16*)((int*)d_ws + o);      o += (size_t)N_NODES * 32;   // N x 64 f16
    f16* h2         = (f16*)((int*)d_ws + o);      o += (size_t)N_NODES * 16;   // N x 32 f16
    float* as1      = (float*)d_ws + o;            o += (size_t)N_NODES * 2;
    float* ad1      = (float*)d_ws + o;            o += (size_t)N_NODES * 2;
    float* as2      = (float*)d_ws + o;            o += (size_t)N_NODES;
    float* ad2      = (float*)d_ws + o;            o += (size_t)N_NODES;
    const int* srcs = (const int*)edges;

    // CSR build
    (void)hipMemsetAsync(bcnt, 0, NB * sizeof(int), stream);
    partition_kernel<<<NPB, 256, 0, stream>>>(src, dst, bcnt, edges);
    bucket_scatter<<<NB, 256, 0, stream>>>(edges, bcnt, rowSD);

    // layer 1 linear
    lin1_kernel<<<N_NODES / 16, 256, 0, stream>>>(x, W1, a1s, a1d, h1, as1, ad1);
    // layer 1 aggregation + fused layer 2 linear
    agg1_kernel<<<N_NODES / 8, 256, 0, stream>>>(rowSD, srcs, h1, as1, ad1, b1,
                                                 W2, a2s, a2d, h2, as2, ad2);
    // layer 2 aggregation
    agg2_kernel<<<N_NODES / 4, 256, 0, stream>>>(rowSD, srcs, h2, as2, ad2, b2, out);
}

// Round 13
// 195.018 us; speedup vs baseline: 1.0743x; 1.0743x over previous
//
#include <hip/hip_runtime.h>
#include <math.h>

#define N_NODES 100000
#define E_EDGES 1600000
#define EA (E_EDGES + N_NODES)   // with self loops
#define NEG_SLOPE 0.2f
#define LG_BUCKET 8
#define BUCKET (1 << LG_BUCKET)            // 256-node dst buckets (R11-proven)
#define NB ((N_NODES + BUCKET - 1) >> LG_BUCKET)   // 391
#define LG_SLOTS 13
#define SLOTS (1 << LG_SLOTS)    // per-bucket slack region (mean fill ~4350)
#define CH 8192                  // edges per block in partition pass (R11-proven)
#define NPB ((EA + CH - 1) / CH) // 208
#define SRC_BITS 17
#define SRC_MASK ((1u << SRC_BITS) - 1)
#define CAP 96                   // per-node LDS softmax cache for agg2 (max deg ~40)

typedef _Float16 f16;
typedef _Float16 half2v __attribute__((ext_vector_type(2)));

__device__ __forceinline__ float leaky(float e) { return e >= 0.f ? e : NEG_SLOPE * e; }
__device__ __forceinline__ unsigned h2u(half2v h) { return __builtin_bit_cast(unsigned, h); }
__device__ __forceinline__ half2v u2h(unsigned u) { return __builtin_bit_cast(half2v, u); }
__device__ __forceinline__ half2v cvtpk(float a, float b) {
    return __builtin_bit_cast(half2v, __builtin_amdgcn_cvt_pkrtz(a, b));
}

// ---------------- CSR build: slack-bucket partition, in-place scatter (R11-proven) ----------------

__global__ __launch_bounds__(256) void partition_kernel(const int* __restrict__ src,
                                                        const int* __restrict__ dst,
                                                        int* __restrict__ bcnt,
                                                        unsigned* __restrict__ edges) {
    __shared__ int hist[NB];
    __shared__ int base[NB];
    int t = threadIdx.x;
    for (int i = t; i < NB; i += 256) hist[i] = 0;
    __syncthreads();
    int e0 = blockIdx.x * CH;
    int e1 = e0 + CH < EA ? e0 + CH : EA;
    for (int e = e0 + t; e < e1; e += 256) {
        int d = (e < E_EDGES) ? dst[e] : (e - E_EDGES);
        atomicAdd(&hist[d >> LG_BUCKET], 1);
    }
    __syncthreads();
    for (int i = t; i < NB; i += 256) {
        int h = hist[i];
        base[i] = h ? atomicAdd(&bcnt[i], h) : 0;
        hist[i] = 0;   // reuse as local cursor
    }
    __syncthreads();
    for (int e = e0 + t; e < e1; e += 256) {
        int s, d;
        if (e < E_EDGES) { s = src[e]; d = dst[e]; } else { s = e - E_EDGES; d = s; }
        int b = d >> LG_BUCKET;
        int r = base[b] + atomicAdd(&hist[b], 1);
        if (r < SLOTS)   // overflow guard (statistically impossible)
            edges[(b << LG_SLOTS) + r] = ((unsigned)(d & (BUCKET - 1)) << SRC_BITS) | (unsigned)s;
    }
}

// per-bucket local scatter (in-place via LDS staging); emits rowSD = {start, deg}
__global__ __launch_bounds__(256) void bucket_scatter(unsigned* __restrict__ edges,
                                                      const int* __restrict__ bcnt,
                                                      int2* __restrict__ rowSD) {
    __shared__ unsigned stage[SLOTS];   // 32 KB
    __shared__ int hist[256];
    __shared__ int sc[256];
    int b = blockIdx.x;
    int t = threadIdx.x;
    int node0 = b << LG_BUCKET;
    int cnt = bcnt[b]; if (cnt > SLOTS) cnt = SLOTS;
    int baseg = b << LG_SLOTS;
    hist[t] = 0;
    __syncthreads();
    for (int i = t; i < cnt; i += 256) {
        unsigned p = edges[baseg + i];
        stage[i] = p;
        atomicAdd(&hist[p >> SRC_BITS], 1);
    }
    __syncthreads();
    int v = hist[t];
    sc[t] = v;
    __syncthreads();
    for (int off = 1; off < 256; off <<= 1) {
        int x = (t >= off) ? sc[t - off] : 0;
        __syncthreads();
        sc[t] += x;
        __syncthreads();
    }
    int excl = sc[t] - v;
    if (t < BUCKET && node0 + t < N_NODES) rowSD[node0 + t] = make_int2(baseg + excl, v);
    hist[t] = excl;   // reuse as cursor
    __syncthreads();
    for (int i = t; i < cnt; i += 256) {
        unsigned p = stage[i];
        int r = atomicAdd(&hist[p >> SRC_BITS], 1);
        edges[baseg + r] = p & SRC_MASK;   // in-place: now plain src index
    }
}

// ---------------- Layer 1: linear + logits (16 rows/block) ----------------

__global__ __launch_bounds__(256) void lin1_kernel(
        const float* __restrict__ x, const float* __restrict__ W1,
        const float* __restrict__ a1s, const float* __restrict__ a1d,
        f16* __restrict__ h1, float* __restrict__ as1, float* __restrict__ ad1) {
    __shared__ float Wl[64 * 64];
    __shared__ float xs[16 * 64];
    int tid = threadIdx.x;
    int r0 = blockIdx.x * 16;
    const float4* W4 = (const float4*)W1;
    float4* Wl4 = (float4*)Wl;
    #pragma unroll
    for (int i = 0; i < 4; i++) Wl4[tid + i * 256] = W4[tid + i * 256];
    ((float4*)xs)[tid] = ((const float4*)(x + (size_t)r0 * 64))[tid];
    __syncthreads();
    int c = tid & 63, tg = tid >> 6;
    float acc0 = 0.f, acc1 = 0.f, acc2 = 0.f, acc3 = 0.f;
    #pragma unroll
    for (int k = 0; k < 64; k++) {
        float w = Wl[k * 64 + c];
        acc0 += xs[(tg * 4 + 0) * 64 + k] * w;
        acc1 += xs[(tg * 4 + 1) * 64 + k] * w;
        acc2 += xs[(tg * 4 + 2) * 64 + k] * w;
        acc3 += xs[(tg * 4 + 3) * 64 + k] * w;
    }
    int r = r0 + tg * 4;
    h1[(size_t)(r + 0) * 64 + c] = (f16)acc0;
    h1[(size_t)(r + 1) * 64 + c] = (f16)acc1;
    h1[(size_t)(r + 2) * 64 + c] = (f16)acc2;
    h1[(size_t)(r + 3) * 64 + c] = (f16)acc3;
    float s_c = a1s[c], d_c = a1d[c];
    float vs0 = acc0 * s_c, vd0 = acc0 * d_c;
    float vs1 = acc1 * s_c, vd1 = acc1 * d_c;
    float vs2 = acc2 * s_c, vd2 = acc2 * d_c;
    float vs3 = acc3 * s_c, vd3 = acc3 * d_c;
    #pragma unroll
    for (int off = 16; off > 0; off >>= 1) {
        vs0 += __shfl_xor(vs0, off); vd0 += __shfl_xor(vd0, off);
        vs1 += __shfl_xor(vs1, off); vd1 += __shfl_xor(vd1, off);
        vs2 += __shfl_xor(vs2, off); vd2 += __shfl_xor(vd2, off);
        vs3 += __shfl_xor(vs3, off); vd3 += __shfl_xor(vd3, off);
    }
    if ((c & 31) == 0) {
        int h = c >> 5;
        as1[(r + 0) * 2 + h] = vs0; ad1[(r + 0) * 2 + h] = vd0;
        as1[(r + 1) * 2 + h] = vs1; ad1[(r + 1) * 2 + h] = vd1;
        as1[(r + 2) * 2 + h] = vs2; ad1[(r + 2) * 2 + h] = vd2;
        as1[(r + 3) * 2 + h] = vs3; ad1[(r + 3) * 2 + h] = vd3;
    }
}

// ---------------- Layer 1 aggregation + fused layer-2 linear (R12-proven) ----------------
// half-wave per node; lane l covers feature pair (2l,2l+1), head hh = l>>4.
// Single pass; shfl-broadcast s and p; head via v_perm splat; v_pk_fma_f16 acc.

__global__ __launch_bounds__(256) void agg1_kernel(
        const int2* __restrict__ rowSD, const int* __restrict__ srcs,
        const f16* __restrict__ h1, const float* __restrict__ as1,
        const float* __restrict__ ad1, const float* __restrict__ b1,
        const float* __restrict__ W2, const float* __restrict__ a2s,
        const float* __restrict__ a2d,
        f16* __restrict__ h2, float* __restrict__ as2, float* __restrict__ ad2) {
    __shared__ float rowb[8][68];
    __shared__ float W2l[64 * 32];
    int tid = threadIdx.x;
    for (int i = tid; i < 2048; i += 256) W2l[i] = W2[i];
    int hwid = tid >> 5;
    int l = tid & 31;
    int hh = l >> 4;
    int v = blockIdx.x * 8 + hwid;
    int2 sd = rowSD[v];
    int start = sd.x, deg = sd.y;
    float2 adv = ((const float2*)ad1)[v];
    const float2* as1v2 = (const float2*)as1;
    const half2v* h1v = (const half2v*)h1;
    unsigned psel = hh ? 0x03020302u : 0x01000100u;   // splat hi16 : lo16
    half2v accA = {}, accB = {};
    float z0 = 0.f, z1 = 0.f;
    for (int c = 0; c < deg; c += 32) {
        int cnt = deg - c; if (cnt > 32) cnt = 32;
        int sreg = 0, pki = 0;
        if (c + l < deg) {
            sreg = srcs[start + c + l];
            float2 a = as1v2[sreg];
            float p0 = __expf(leaky(a.x + adv.x));
            float p1 = __expf(leaky(a.y + adv.y));
            half2v pk = cvtpk(p0, p1);
            z0 += (float)pk.x;   // z from rounded p: cancels RTZ bias
            z1 += (float)pk.y;
            pki = (int)h2u(pk);
        }
        int j = 0;
        for (; j + 7 < cnt; j += 8) {
            int s0 = __shfl(sreg, j, 32),     s1 = __shfl(sreg, j + 1, 32);
            int s2 = __shfl(sreg, j + 2, 32), s3 = __shfl(sreg, j + 3, 32);
            int s4 = __shfl(sreg, j + 4, 32), s5 = __shfl(sreg, j + 5, 32);
            int s6 = __shfl(sreg, j + 6, 32), s7 = __shfl(sreg, j + 7, 32);
            unsigned u0 = (unsigned)__shfl(pki, j, 32);
            unsigned u1 = (unsigned)__shfl(pki, j + 1, 32);
            unsigned u2 = (unsigned)__shfl(pki, j + 2, 32);
            unsigned u3 = (unsigned)__shfl(pki, j + 3, 32);
            unsigned u4 = (unsigned)__shfl(pki, j + 4, 32);
            unsigned u5 = (unsigned)__shfl(pki, j + 5, 32);
            unsigned u6 = (unsigned)__shfl(pki, j + 6, 32);
            unsigned u7 = (unsigned)__shfl(pki, j + 7, 32);
            half2v g0 = h1v[s0 * 32 + l];
            half2v g1 = h1v[s1 * 32 + l];
            half2v g2 = h1v[s2 * 32 + l];
            half2v g3 = h1v[s3 * 32 + l];
            half2v g4 = h1v[s4 * 32 + l];
            half2v g5 = h1v[s5 * 32 + l];
            half2v g6 = h1v[s6 * 32 + l];
            half2v g7 = h1v[s7 * 32 + l];
            accA += u2h(__builtin_amdgcn_perm(u0, u0, psel)) * g0;
            accA += u2h(__builtin_amdgcn_perm(u1, u1, psel)) * g1;
            accB += u2h(__builtin_amdgcn_perm(u2, u2, psel)) * g2;
            accB += u2h(__builtin_amdgcn_perm(u3, u3, psel)) * g3;
            accA += u2h(__builtin_amdgcn_perm(u4, u4, psel)) * g4;
            accA += u2h(__builtin_amdgcn_perm(u5, u5, psel)) * g5;
            accB += u2h(__builtin_amdgcn_perm(u6, u6, psel)) * g6;
            accB += u2h(__builtin_amdgcn_perm(u7, u7, psel)) * g7;
        }
        for (; j + 3 < cnt; j += 4) {
            int s0 = __shfl(sreg, j, 32),     s1 = __shfl(sreg, j + 1, 32);
            int s2 = __shfl(sreg, j + 2, 32), s3 = __shfl(sreg, j + 3, 32);
            unsigned u0 = (unsigned)__shfl(pki, j, 32);
            unsigned u1 = (unsigned)__shfl(pki, j + 1, 32);
            unsigned u2 = (unsigned)__shfl(pki, j + 2, 32);
            unsigned u3 = (unsigned)__shfl(pki, j + 3, 32);
            half2v g0 = h1v[s0 * 32 + l];
            half2v g1 = h1v[s1 * 32 + l];
            half2v g2 = h1v[s2 * 32 + l];
            half2v g3 = h1v[s3 * 32 + l];
            accA += u2h(__builtin_amdgcn_perm(u0, u0, psel)) * g0;
            accA += u2h(__builtin_amdgcn_perm(u1, u1, psel)) * g1;
            accB += u2h(__builtin_amdgcn_perm(u2, u2, psel)) * g2;
            accB += u2h(__builtin_amdgcn_perm(u3, u3, psel)) * g3;
        }
        for (; j < cnt; j++) {
            int s0 = __shfl(sreg, j, 32);
            unsigned u0 = (unsigned)__shfl(pki, j, 32);
            half2v g0 = h1v[s0 * 32 + l];
            accA += u2h(__builtin_amdgcn_perm(u0, u0, psel)) * g0;
        }
    }
    #pragma unroll
    for (int off = 16; off > 0; off >>= 1) {
        z0 += __shfl_xor(z0, off);
        z1 += __shfl_xor(z1, off);
    }
    float rz = 1.f / (hh ? z1 : z0);
    half2v accT = accA + accB;
    float o0 = (float)accT.x * rz + b1[2 * l];
    float o1 = (float)accT.y * rz + b1[2 * l + 1];
    o0 = o0 > 0.f ? o0 : __expf(o0) - 1.f;
    o1 = o1 > 0.f ? o1 : __expf(o1) - 1.f;
    rowb[hwid][2 * l] = o0;
    rowb[hwid][2 * l + 1] = o1;
    __syncthreads();   // covers W2l staging (and rowb, though same-wave)
    float hc = 0.f;
    #pragma unroll 8
    for (int k = 0; k < 64; k++) hc += rowb[hwid][k] * W2l[k * 32 + l];
    h2[(size_t)v * 32 + l] = (f16)hc;
    float vs = hc * a2s[l], vd = hc * a2d[l];
    #pragma unroll
    for (int off = 16; off > 0; off >>= 1) { vs += __shfl_xor(vs, off); vd += __shfl_xor(vd, off); }
    if (l == 0) { as2[v] = vs; ad2[v] = vd; }
}

// ---------------- Layer 2: aggregation (R8 structure; pass-2 -> 8 lanes/edge uint2) ----------------

__global__ __launch_bounds__(256) void agg2_kernel(
        const int2* __restrict__ rowSD, const int* __restrict__ srcs,
        const f16* __restrict__ h2, const float* __restrict__ as2,
        const float* __restrict__ ad2, const float* __restrict__ b2,
        float* __restrict__ out) {
    __shared__ float pbuf2[4][CAP];
    int wid = threadIdx.x >> 6;
    int v = blockIdx.x * 4 + wid;
    int lane = threadIdx.x & 63;
    int2 sd = rowSD[v];
    int start = sd.x, deg = sd.y;
    float adv = ad2[v];
    float z = 0.f;
    if (deg <= CAP) {
        // pass 1 (R8-proven): p = exp(leaky(logit)), cache in LDS, sum (full wave)
        for (int idx = lane; idx < deg; idx += 64) {
            int s = srcs[start + idx];
            float p = __expf(leaky(as2[s] + adv));
            pbuf2[wid][idx] = p;
            z += p;
        }
        #pragma unroll
        for (int off = 32; off > 0; off >>= 1) z += __shfl_xor(z, off);
        // pass 2 (new): 8 lanes per edge, each lane loads 4 f16 features (uint2);
        // 8 edges in flight per wave, unroll x2
        int q8 = lane >> 3, f8 = lane & 7;
        const uint2* h2q = (const uint2*)h2;   // row = 8 uint2 (32 f16)
        float a0 = 0.f, a1 = 0.f, a2 = 0.f, a3 = 0.f;
        int idx = q8;
        for (; idx + 8 < deg; idx += 16) {
            int s0 = srcs[start + idx];
            int s1 = srcs[start + idx + 8];
            float p0 = pbuf2[wid][idx];
            float p1 = pbuf2[wid][idx + 8];
            uint2 g0 = h2q[(size_t)s0 * 8 + f8];
            uint2 g1 = h2q[(size_t)s1 * 8 + f8];
            half2v l0 = u2h(g0.x), hi0 = u2h(g0.y);
            half2v l1 = u2h(g1.x), hi1 = u2h(g1.y);
            a0 += p0 * (float)l0.x  + p1 * (float)l1.x;
            a1 += p0 * (float)l0.y  + p1 * (float)l1.y;
            a2 += p0 * (float)hi0.x + p1 * (float)hi1.x;
            a3 += p0 * (float)hi0.y + p1 * (float)hi1.y;
        }
        if (idx < deg) {
            int s0 = srcs[start + idx];
            float p0 = pbuf2[wid][idx];
            uint2 g0 = h2q[(size_t)s0 * 8 + f8];
            half2v l0 = u2h(g0.x), hi0 = u2h(g0.y);
            a0 += p0 * (float)l0.x;
            a1 += p0 * (float)l0.y;
            a2 += p0 * (float)hi0.x;
            a3 += p0 * (float)hi0.y;
        }
        // reduce across the 8 edge-groups (lanes with equal f8)
        #pragma unroll
        for (int off = 8; off < 64; off <<= 1) {
            a0 += __shfl_xor(a0, off);
            a1 += __shfl_xor(a1, off);
            a2 += __shfl_xor(a2, off);
            a3 += __shfl_xor(a3, off);
        }
        if (lane < 8) {
            float rz = 1.f / z;
            float4 r;
            r.x = a0 * rz + b2[4 * f8];
            r.y = a1 * rz + b2[4 * f8 + 1];
            r.z = a2 * rz + b2[4 * f8 + 2];
            r.w = a3 * rz + b2[4 * f8 + 3];
            ((float4*)out)[(size_t)v * 8 + f8] = r;
        }
    } else {
        // slow path (deg > CAP; never for this input): R8 3-pass with max, 16 lanes/edge
        int q = lane >> 4, f = lane & 15;
        const half2v* h2v = (const half2v*)h2;
        float a0 = 0.f, a1 = 0.f;
        float m = -1e30f;
        for (int idx = lane; idx < deg; idx += 64)
            m = fmaxf(m, leaky(as2[srcs[start + idx]] + adv));
        #pragma unroll
        for (int off = 32; off > 0; off >>= 1) m = fmaxf(m, __shfl_xor(m, off));
        for (int idx = lane; idx < deg; idx += 64)
            z += __expf(leaky(as2[srcs[start + idx]] + adv) - m);
        #pragma unroll
        for (int off = 32; off > 0; off >>= 1) z += __shfl_xor(z, off);
        for (int idx = q; idx < deg; idx += 4) {
            int s0 = srcs[start + idx];
            float p0 = __expf(leaky(as2[s0] + adv) - m);
            half2v g0 = h2v[(size_t)s0 * 16 + f];
            a0 += p0 * (float)g0.x; a1 += p0 * (float)g0.y;
        }
        a0 += __shfl_xor(a0, 16); a1 += __shfl_xor(a1, 16);
        a0 += __shfl_xor(a0, 32); a1 += __shfl_xor(a1, 32);
        if (lane < 16) {
            float rz = 1.f / z;
            float2 r;
            r.x = a0 * rz + b2[2 * f];
            r.y = a1 * rz + b2[2 * f + 1];
            ((float2*)out)[(size_t)v * 16 + f] = r;
        }
    }
}

// ---------------- launch ----------------

extern "C" void kernel_launch(void* const* d_in, const int* in_sizes, int n_in,
                              void* d_out, int out_size, void* d_ws, size_t ws_size,
                              hipStream_t stream) {
    const float* x    = (const float*)d_in[0];
    const int*   ei   = (const int*)d_in[1];
    const float* W1   = (const float*)d_in[2];
    const float* a1s  = (const float*)d_in[3];
    const float* a1d  = (const float*)d_in[4];
    const float* b1   = (const float*)d_in[5];
    const float* W2   = (const float*)d_in[6];
    const float* a2s  = (const float*)d_in[7];
    const float* a2d  = (const float*)d_in[8];
    const float* b2   = (const float*)d_in[9];
    const int* src = ei;
    const int* dst = ei + E_EDGES;
    float* out = (float*)d_out;

    // workspace layout (4-byte words, 64-word aligned regions) — total ~35.2 MB (proven)
    size_t o = 0;
    int2* rowSD     = (int2*)((int*)d_ws + o);     o += ((2 * N_NODES + 63) / 64) * 64;
    int* bcnt       = (int*)d_ws + o;              o += ((NB + 63) / 64) * 64;
    unsigned* edges = (unsigned*)((int*)d_ws + o); o += (size_t)NB * SLOTS;   // packed, then in-place srcs
    f16* h1         = (f16*)((int*)d_ws + o);      o += (size_t)N_NODES * 32;   // N x 64 f16
    f16* h2         = (f16*)((int*)d_ws + o);      o += (size_t)N_NODES * 16;   // N x 32 f16
    float* as1      = (float*)d_ws + o;            o += (size_t)N_NODES * 2;
    float* ad1      = (float*)d_ws + o;            o += (size_t)N_NODES * 2;
    float* as2      = (float*)d_ws + o;            o += (size_t)N_NODES;
    float* ad2      = (float*)d_ws + o;            o += (size_t)N_NODES;
    const int* srcs = (const int*)edges;

    // CSR build
    (void)hipMemsetAsync(bcnt, 0, NB * sizeof(int), stream);
    partition_kernel<<<NPB, 256, 0, stream>>>(src, dst, bcnt, edges);
    bucket_scatter<<<NB, 256, 0, stream>>>(edges, bcnt, rowSD);

    // layer 1 linear
    lin1_kernel<<<N_NODES / 16, 256, 0, stream>>>(x, W1, a1s, a1d, h1, as1, ad1);
    // layer 1 aggregation + fused layer 2 linear
    agg1_kernel<<<N_NODES / 8, 256, 0, stream>>>(rowSD, srcs, h1, as1, ad1, b1,
                                                 W2, a2s, a2d, h2, as2, ad2);
    // layer 2 aggregation
    agg2_kernel<<<N_NODES / 4, 256, 0, stream>>>(rowSD, srcs, h2, as2, ad2, b2, out);
}

// Round 14
// 184.814 us; speedup vs baseline: 1.1336x; 1.0552x over previous
//
#include <hip/hip_runtime.h>
#include <math.h>

#define N_NODES 100000
#define E_EDGES 1600000
#define EA (E_EDGES + N_NODES)   // with self loops
#define NEG_SLOPE 0.2f
#define LG_BUCKET 8
#define BUCKET (1 << LG_BUCKET)            // 256-node dst buckets (R11-proven)
#define NB ((N_NODES + BUCKET - 1) >> LG_BUCKET)   // 391
#define LG_SLOTS 13
#define SLOTS (1 << LG_SLOTS)    // per-bucket slack region (mean fill ~4350)
#define CH 8192                  // edges per block in partition pass (R11-proven)
#define NPB ((EA + CH - 1) / CH) // 208
#define SRC_BITS 17
#define SRC_MASK ((1u << SRC_BITS) - 1)
#define CAP 96                   // per-node LDS softmax cache for agg2 (max deg ~40)

typedef _Float16 f16;
typedef _Float16 half2v __attribute__((ext_vector_type(2)));

__device__ __forceinline__ float leaky(float e) { return e >= 0.f ? e : NEG_SLOPE * e; }
__device__ __forceinline__ unsigned h2u(half2v h) { return __builtin_bit_cast(unsigned, h); }
__device__ __forceinline__ half2v u2h(unsigned u) { return __builtin_bit_cast(half2v, u); }
__device__ __forceinline__ half2v cvtpk(float a, float b) {
    return __builtin_bit_cast(half2v, __builtin_amdgcn_cvt_pkrtz(a, b));
}

// ---------------- CSR build: slack-bucket partition, in-place scatter (R11-proven) ----------------

__global__ __launch_bounds__(256) void partition_kernel(const int* __restrict__ src,
                                                        const int* __restrict__ dst,
                                                        int* __restrict__ bcnt,
                                                        unsigned* __restrict__ edges) {
    __shared__ int hist[NB];
    __shared__ int base[NB];
    int t = threadIdx.x;
    for (int i = t; i < NB; i += 256) hist[i] = 0;
    __syncthreads();
    int e0 = blockIdx.x * CH;
    int e1 = e0 + CH < EA ? e0 + CH : EA;
    for (int e = e0 + t; e < e1; e += 256) {
        int d = (e < E_EDGES) ? dst[e] : (e - E_EDGES);
        atomicAdd(&hist[d >> LG_BUCKET], 1);
    }
    __syncthreads();
    for (int i = t; i < NB; i += 256) {
        int h = hist[i];
        base[i] = h ? atomicAdd(&bcnt[i], h) : 0;
        hist[i] = 0;   // reuse as local cursor
    }
    __syncthreads();
    for (int e = e0 + t; e < e1; e += 256) {
        int s, d;
        if (e < E_EDGES) { s = src[e]; d = dst[e]; } else { s = e - E_EDGES; d = s; }
        int b = d >> LG_BUCKET;
        int r = base[b] + atomicAdd(&hist[b], 1);
        if (r < SLOTS)   // overflow guard (statistically impossible)
            edges[(b << LG_SLOTS) + r] = ((unsigned)(d & (BUCKET - 1)) << SRC_BITS) | (unsigned)s;
    }
}

// per-bucket local scatter (in-place via LDS staging); emits rowSD = {start, deg}
__global__ __launch_bounds__(256) void bucket_scatter(unsigned* __restrict__ edges,
                                                      const int* __restrict__ bcnt,
                                                      int2* __restrict__ rowSD) {
    __shared__ unsigned stage[SLOTS];   // 32 KB
    __shared__ int hist[256];
    __shared__ int sc[256];
    int b = blockIdx.x;
    int t = threadIdx.x;
    int node0 = b << LG_BUCKET;
    int cnt = bcnt[b]; if (cnt > SLOTS) cnt = SLOTS;
    int baseg = b << LG_SLOTS;
    hist[t] = 0;
    __syncthreads();
    for (int i = t; i < cnt; i += 256) {
        unsigned p = edges[baseg + i];
        stage[i] = p;
        atomicAdd(&hist[p >> SRC_BITS], 1);
    }
    __syncthreads();
    int v = hist[t];
    sc[t] = v;
    __syncthreads();
    for (int off = 1; off < 256; off <<= 1) {
        int x = (t >= off) ? sc[t - off] : 0;
        __syncthreads();
        sc[t] += x;
        __syncthreads();
    }
    int excl = sc[t] - v;
    if (t < BUCKET && node0 + t < N_NODES) rowSD[node0 + t] = make_int2(baseg + excl, v);
    hist[t] = excl;   // reuse as cursor
    __syncthreads();
    for (int i = t; i < cnt; i += 256) {
        unsigned p = stage[i];
        int r = atomicAdd(&hist[p >> SRC_BITS], 1);
        edges[baseg + r] = p & SRC_MASK;   // in-place: now plain src index
    }
}

// ---------------- Layer 1: linear + logits (16 rows/block) ----------------

__global__ __launch_bounds__(256) void lin1_kernel(
        const float* __restrict__ x, const float* __restrict__ W1,
        const float* __restrict__ a1s, const float* __restrict__ a1d,
        f16* __restrict__ h1, float* __restrict__ as1, float* __restrict__ ad1) {
    __shared__ float Wl[64 * 64];
    __shared__ float xs[16 * 64];
    int tid = threadIdx.x;
    int r0 = blockIdx.x * 16;
    const float4* W4 = (const float4*)W1;
    float4* Wl4 = (float4*)Wl;
    #pragma unroll
    for (int i = 0; i < 4; i++) Wl4[tid + i * 256] = W4[tid + i * 256];
    ((float4*)xs)[tid] = ((const float4*)(x + (size_t)r0 * 64))[tid];
    __syncthreads();
    int c = tid & 63, tg = tid >> 6;
    float acc0 = 0.f, acc1 = 0.f, acc2 = 0.f, acc3 = 0.f;
    #pragma unroll
    for (int k = 0; k < 64; k++) {
        float w = Wl[k * 64 + c];
        acc0 += xs[(tg * 4 + 0) * 64 + k] * w;
        acc1 += xs[(tg * 4 + 1) * 64 + k] * w;
        acc2 += xs[(tg * 4 + 2) * 64 + k] * w;
        acc3 += xs[(tg * 4 + 3) * 64 + k] * w;
    }
    int r = r0 + tg * 4;
    h1[(size_t)(r + 0) * 64 + c] = (f16)acc0;
    h1[(size_t)(r + 1) * 64 + c] = (f16)acc1;
    h1[(size_t)(r + 2) * 64 + c] = (f16)acc2;
    h1[(size_t)(r + 3) * 64 + c] = (f16)acc3;
    float s_c = a1s[c], d_c = a1d[c];
    float vs0 = acc0 * s_c, vd0 = acc0 * d_c;
    float vs1 = acc1 * s_c, vd1 = acc1 * d_c;
    float vs2 = acc2 * s_c, vd2 = acc2 * d_c;
    float vs3 = acc3 * s_c, vd3 = acc3 * d_c;
    #pragma unroll
    for (int off = 16; off > 0; off >>= 1) {
        vs0 += __shfl_xor(vs0, off); vd0 += __shfl_xor(vd0, off);
        vs1 += __shfl_xor(vs1, off); vd1 += __shfl_xor(vd1, off);
        vs2 += __shfl_xor(vs2, off); vd2 += __shfl_xor(vd2, off);
        vs3 += __shfl_xor(vs3, off); vd3 += __shfl_xor(vd3, off);
    }
    if ((c & 31) == 0) {
        int h = c >> 5;
        as1[(r + 0) * 2 + h] = vs0; ad1[(r + 0) * 2 + h] = vd0;
        as1[(r + 1) * 2 + h] = vs1; ad1[(r + 1) * 2 + h] = vd1;
        as1[(r + 2) * 2 + h] = vs2; ad1[(r + 2) * 2 + h] = vd2;
        as1[(r + 3) * 2 + h] = vs3; ad1[(r + 3) * 2 + h] = vd3;
    }
}

// ---------------- Layer 1 aggregation + fused layer-2 linear (quarter-wave) ----------------
// 16 lanes per node; lane l covers features 4l..4l+3 (one uint2 = 4 f16), head hh = l>>3.
// Single pass (R11-proven softmax scheme): per 16-edge chunk each lane computes its
// edge's p (both heads, cvt_pkrtz-packed); inner loop shfl-broadcasts s and p within
// the 16-lane group; head via v_perm splat; v_pk_fma_f16 accumulate. 4 nodes per wave.

__global__ __launch_bounds__(256) void agg1_kernel(
        const int2* __restrict__ rowSD, const int* __restrict__ srcs,
        const f16* __restrict__ h1, const float* __restrict__ as1,
        const float* __restrict__ ad1, const float* __restrict__ b1,
        const float* __restrict__ W2, const float* __restrict__ a2s,
        const float* __restrict__ a2d,
        f16* __restrict__ h2, float* __restrict__ as2, float* __restrict__ ad2) {
    __shared__ float rowb[16][68];
    __shared__ float W2l[64 * 32];
    int tid = threadIdx.x;
    for (int i = tid; i < 2048; i += 256) W2l[i] = W2[i];
    int qwid = tid >> 4;        // 0..15 quarter-wave id
    int l = tid & 15;           // lane in quarter
    int hh = l >> 3;            // head for this lane's 4 features
    int v = blockIdx.x * 16 + qwid;
    int2 sd = rowSD[v];
    int start = sd.x, deg = sd.y;
    float2 adv = ((const float2*)ad1)[v];
    const float2* as1v2 = (const float2*)as1;
    const uint2* h1q = (const uint2*)h1;   // row = 16 uint2 (64 f16)
    unsigned psel = hh ? 0x03020302u : 0x01000100u;   // splat hi16 : lo16
    half2v ax0 = {}, ax1 = {}, bx0 = {}, bx1 = {};
    float z0 = 0.f, z1 = 0.f;
    for (int c = 0; c < deg; c += 16) {
        int cnt = deg - c; if (cnt > 16) cnt = 16;
        int sreg = 0, pki = 0;
        if (c + l < deg) {
            sreg = srcs[start + c + l];
            float2 a = as1v2[sreg];
            half2v pk = cvtpk(__expf(leaky(a.x + adv.x)), __expf(leaky(a.y + adv.y)));
            z0 += (float)pk.x;   // z from rounded p: cancels RTZ bias
            z1 += (float)pk.y;
            pki = (int)h2u(pk);
        }
        int j = 0;
        for (; j + 3 < cnt; j += 4) {
            int s0 = __shfl(sreg, j, 16),     s1 = __shfl(sreg, j + 1, 16);
            int s2 = __shfl(sreg, j + 2, 16), s3 = __shfl(sreg, j + 3, 16);
            unsigned u0 = (unsigned)__shfl(pki, j, 16);
            unsigned u1 = (unsigned)__shfl(pki, j + 1, 16);
            unsigned u2 = (unsigned)__shfl(pki, j + 2, 16);
            unsigned u3 = (unsigned)__shfl(pki, j + 3, 16);
            uint2 g0 = h1q[(size_t)s0 * 16 + l];
            uint2 g1 = h1q[(size_t)s1 * 16 + l];
            uint2 g2 = h1q[(size_t)s2 * 16 + l];
            uint2 g3 = h1q[(size_t)s3 * 16 + l];
            half2v p0 = u2h(__builtin_amdgcn_perm(u0, u0, psel));
            half2v p1 = u2h(__builtin_amdgcn_perm(u1, u1, psel));
            half2v p2 = u2h(__builtin_amdgcn_perm(u2, u2, psel));
            half2v p3 = u2h(__builtin_amdgcn_perm(u3, u3, psel));
            ax0 += p0 * u2h(g0.x); ax1 += p0 * u2h(g0.y);
            ax0 += p1 * u2h(g1.x); ax1 += p1 * u2h(g1.y);
            bx0 += p2 * u2h(g2.x); bx1 += p2 * u2h(g2.y);
            bx0 += p3 * u2h(g3.x); bx1 += p3 * u2h(g3.y);
        }
        for (; j < cnt; j++) {
            int s0 = __shfl(sreg, j, 16);
            unsigned u0 = (unsigned)__shfl(pki, j, 16);
            uint2 g0 = h1q[(size_t)s0 * 16 + l];
            half2v p0 = u2h(__builtin_amdgcn_perm(u0, u0, psel));
            ax0 += p0 * u2h(g0.x); ax1 += p0 * u2h(g0.y);
        }
    }
    // z reduce across the 16-lane quarter
    #pragma unroll
    for (int off = 8; off > 0; off >>= 1) {
        z0 += __shfl_xor(z0, off);
        z1 += __shfl_xor(z1, off);
    }
    // epilogue: elu(out1) -> LDS row; fused lin2
    float rz = 1.f / (hh ? z1 : z0);
    half2v t0 = ax0 + bx0;   // features 4l, 4l+1
    half2v t1 = ax1 + bx1;   // features 4l+2, 4l+3
    float o0 = (float)t0.x * rz + b1[4 * l];
    float o1 = (float)t0.y * rz + b1[4 * l + 1];
    float o2 = (float)t1.x * rz + b1[4 * l + 2];
    float o3 = (float)t1.y * rz + b1[4 * l + 3];
    o0 = o0 > 0.f ? o0 : __expf(o0) - 1.f;
    o1 = o1 > 0.f ? o1 : __expf(o1) - 1.f;
    o2 = o2 > 0.f ? o2 : __expf(o2) - 1.f;
    o3 = o3 > 0.f ? o3 : __expf(o3) - 1.f;
    rowb[qwid][4 * l]     = o0;
    rowb[qwid][4 * l + 1] = o1;
    rowb[qwid][4 * l + 2] = o2;
    rowb[qwid][4 * l + 3] = o3;
    __syncthreads();   // covers W2l staging (rowb is same-wave)
    // fused lin2: lane computes h2 columns 2l, 2l+1
    float hc0 = 0.f, hc1 = 0.f;
    #pragma unroll 8
    for (int k = 0; k < 64; k++) {
        float r = rowb[qwid][k];
        hc0 += r * W2l[k * 32 + 2 * l];
        hc1 += r * W2l[k * 32 + 2 * l + 1];
    }
    h2[(size_t)v * 32 + 2 * l]     = (f16)hc0;
    h2[(size_t)v * 32 + 2 * l + 1] = (f16)hc1;
    float vs = hc0 * a2s[2 * l] + hc1 * a2s[2 * l + 1];
    float vd = hc0 * a2d[2 * l] + hc1 * a2d[2 * l + 1];
    #pragma unroll
    for (int off = 8; off > 0; off >>= 1) { vs += __shfl_xor(vs, off); vd += __shfl_xor(vd, off); }
    if (l == 0) { as2[v] = vs; ad2[v] = vd; }
}

// ---------------- Layer 2: aggregation (R13-proven, verbatim) ----------------

__global__ __launch_bounds__(256) void agg2_kernel(
        const int2* __restrict__ rowSD, const int* __restrict__ srcs,
        const f16* __restrict__ h2, const float* __restrict__ as2,
        const float* __restrict__ ad2, const float* __restrict__ b2,
        float* __restrict__ out) {
    __shared__ float pbuf2[4][CAP];
    int wid = threadIdx.x >> 6;
    int v = blockIdx.x * 4 + wid;
    int lane = threadIdx.x & 63;
    int2 sd = rowSD[v];
    int start = sd.x, deg = sd.y;
    float adv = ad2[v];
    float z = 0.f;
    if (deg <= CAP) {
        for (int idx = lane; idx < deg; idx += 64) {
            int s = srcs[start + idx];
            float p = __expf(leaky(as2[s] + adv));
            pbuf2[wid][idx] = p;
            z += p;
        }
        #pragma unroll
        for (int off = 32; off > 0; off >>= 1) z += __shfl_xor(z, off);
        int q8 = lane >> 3, f8 = lane & 7;
        const uint2* h2q = (const uint2*)h2;   // row = 8 uint2 (32 f16)
        float a0 = 0.f, a1 = 0.f, a2 = 0.f, a3 = 0.f;
        int idx = q8;
        for (; idx + 8 < deg; idx += 16) {
            int s0 = srcs[start + idx];
            int s1 = srcs[start + idx + 8];
            float p0 = pbuf2[wid][idx];
            float p1 = pbuf2[wid][idx + 8];
            uint2 g0 = h2q[(size_t)s0 * 8 + f8];
            uint2 g1 = h2q[(size_t)s1 * 8 + f8];
            half2v l0 = u2h(g0.x), hi0 = u2h(g0.y);
            half2v l1 = u2h(g1.x), hi1 = u2h(g1.y);
            a0 += p0 * (float)l0.x  + p1 * (float)l1.x;
            a1 += p0 * (float)l0.y  + p1 * (float)l1.y;
            a2 += p0 * (float)hi0.x + p1 * (float)hi1.x;
            a3 += p0 * (float)hi0.y + p1 * (float)hi1.y;
        }
        if (idx < deg) {
            int s0 = srcs[start + idx];
            float p0 = pbuf2[wid][idx];
            uint2 g0 = h2q[(size_t)s0 * 8 + f8];
            half2v l0 = u2h(g0.x), hi0 = u2h(g0.y);
            a0 += p0 * (float)l0.x;
            a1 += p0 * (float)l0.y;
            a2 += p0 * (float)hi0.x;
            a3 += p0 * (float)hi0.y;
        }
        #pragma unroll
        for (int off = 8; off < 64; off <<= 1) {
            a0 += __shfl_xor(a0, off);
            a1 += __shfl_xor(a1, off);
            a2 += __shfl_xor(a2, off);
            a3 += __shfl_xor(a3, off);
        }
        if (lane < 8) {
            float rz = 1.f / z;
            float4 r;
            r.x = a0 * rz + b2[4 * f8];
            r.y = a1 * rz + b2[4 * f8 + 1];
            r.z = a2 * rz + b2[4 * f8 + 2];
            r.w = a3 * rz + b2[4 * f8 + 3];
            ((float4*)out)[(size_t)v * 8 + f8] = r;
        }
    } else {
        int q = lane >> 4, f = lane & 15;
        const half2v* h2v = (const half2v*)h2;
        float a0 = 0.f, a1 = 0.f;
        float m = -1e30f;
        for (int idx = lane; idx < deg; idx += 64)
            m = fmaxf(m, leaky(as2[srcs[start + idx]] + adv));
        #pragma unroll
        for (int off = 32; off > 0; off >>= 1) m = fmaxf(m, __shfl_xor(m, off));
        for (int idx = lane; idx < deg; idx += 64)
            z += __expf(leaky(as2[srcs[start + idx]] + adv) - m);
        #pragma unroll
        for (int off = 32; off > 0; off >>= 1) z += __shfl_xor(z, off);
        for (int idx = q; idx < deg; idx += 4) {
            int s0 = srcs[start + idx];
            float p0 = __expf(leaky(as2[s0] + adv) - m);
            half2v g0 = h2v[(size_t)s0 * 16 + f];
            a0 += p0 * (float)g0.x; a1 += p0 * (float)g0.y;
        }
        a0 += __shfl_xor(a0, 16); a1 += __shfl_xor(a1, 16);
        a0 += __shfl_xor(a0, 32); a1 += __shfl_xor(a1, 32);
        if (lane < 16) {
            float rz = 1.f / z;
            float2 r;
            r.x = a0 * rz + b2[2 * f];
            r.y = a1 * rz + b2[2 * f + 1];
            ((float2*)out)[(size_t)v * 16 + f] = r;
        }
    }
}

// ---------------- launch ----------------

extern "C" void kernel_launch(void* const* d_in, const int* in_sizes, int n_in,
                              void* d_out, int out_size, void* d_ws, size_t ws_size,
                              hipStream_t stream) {
    const float* x    = (const float*)d_in[0];
    const int*   ei   = (const int*)d_in[1];
    const float* W1   = (const float*)d_in[2];
    const float* a1s  = (const float*)d_in[3];
    const float* a1d  = (const float*)d_in[4];
    const float* b1   = (const float*)d_in[5];
    const float* W2   = (const float*)d_in[6];
    const float* a2s  = (const float*)d_in[7];
    const float* a2d  = (const float*)d_in[8];
    const float* b2   = (const float*)d_in[9];
    const int* src = ei;
    const int* dst = ei + E_EDGES;
    float* out = (float*)d_out;

    // workspace layout (4-byte words, 64-word aligned regions) — total ~35.2 MB (proven)
    size_t o = 0;
    int2* rowSD     = (int2*)((int*)d_ws + o);     o += ((2 * N_NODES + 63) / 64) * 64;
    int* bcnt       = (int*)d_ws + o;              o += ((NB + 63) / 64) * 64;
    unsigned* edges = (unsigned*)((int*)d_ws + o); o += (size_t)NB * SLOTS;   // packed, then in-place srcs
    f16* h1         = (f16*)((int*)d_ws + o);      o += (size_t)N_NODES * 32;   // N x 64 f16
    f16* h2         = (f16*)((int*)d_ws + o);      o += (size_t)N_NODES * 16;   // N x 32 f16
    float* as1      = (float*)d_ws + o;            o += (size_t)N_NODES * 2;
    float* ad1      = (float*)d_ws + o;            o += (size_t)N_NODES * 2;
    float* as2      = (float*)d_ws + o;            o += (size_t)N_NODES;
    float* ad2      = (float*)d_ws + o;            o += (size_t)N_NODES;
    const int* srcs = (const int*)edges;

    // CSR build
    (void)hipMemsetAsync(bcnt, 0, NB * sizeof(int), stream);
    partition_kernel<<<NPB, 256, 0, stream>>>(src, dst, bcnt, edges);
    bucket_scatter<<<NB, 256, 0, stream>>>(edges, bcnt, rowSD);

    // layer 1 linear
    lin1_kernel<<<N_NODES / 16, 256, 0, stream>>>(x, W1, a1s, a1d, h1, as1, ad1);
    // layer 1 aggregation + fused layer 2 linear (quarter-wave: 16 nodes/block)
    agg1_kernel<<<N_NODES / 16, 256, 0, stream>>>(rowSD, srcs, h1, as1, ad1, b1,
                                                  W2, a2s, a2d, h2, as2, ad2);
    // layer 2 aggregation
    agg2_kernel<<<N_NODES / 4, 256, 0, stream>>>(rowSD, srcs, h2, as2, ad2, b2, out);
}

// Round 15
// 153.662 us; speedup vs baseline: 1.3634x; 1.2027x over previous
//
#include <hip/hip_runtime.h>
#include <math.h>

#define N_NODES 100000
#define E_EDGES 1600000
#define EA (E_EDGES + N_NODES)   // with self loops
#define NEG_SLOPE 0.2f
#define LG_BUCKET 8
#define BUCKET (1 << LG_BUCKET)            // 256-node dst buckets (R11-proven)
#define NB ((N_NODES + BUCKET - 1) >> LG_BUCKET)   // 391
#define LG_SLOTS 13
#define SLOTS (1 << LG_SLOTS)    // per-bucket slack region (mean fill ~4350)
#define CH 8192                  // edges per block in partition pass (R11-proven)
#define NPB ((EA + CH - 1) / CH) // 208
#define NLIN1 (N_NODES / 16)     // lin1 blocks (fused behind partition)
#define SRC_BITS 17
#define SRC_MASK ((1u << SRC_BITS) - 1)
#define CAP 96                   // per-node LDS softmax cache for agg2 (max deg ~40)

typedef _Float16 f16;
typedef _Float16 half2v __attribute__((ext_vector_type(2)));

__device__ __forceinline__ float leaky(float e) { return e >= 0.f ? e : NEG_SLOPE * e; }
__device__ __forceinline__ unsigned h2u(half2v h) { return __builtin_bit_cast(unsigned, h); }
__device__ __forceinline__ half2v u2h(unsigned u) { return __builtin_bit_cast(half2v, u); }
__device__ __forceinline__ half2v cvtpk(float a, float b) {
    return __builtin_bit_cast(half2v, __builtin_amdgcn_cvt_pkrtz(a, b));
}

// ---------------- Fat kernel: CSR partition (blocks 0..NPB-1) + lin1 (rest) ----------------
// The two bodies are independent (partition reads edge_index; lin1 reads x/W1),
// so fusing removes lin1's serial slot in the single-stream chain.

__global__ __launch_bounds__(256) void part_lin1_kernel(
        const int* __restrict__ src, const int* __restrict__ dst,
        int* __restrict__ bcnt, unsigned* __restrict__ edges,
        const float* __restrict__ x, const float* __restrict__ W1,
        const float* __restrict__ a1s, const float* __restrict__ a1d,
        f16* __restrict__ h1, float* __restrict__ as1, float* __restrict__ ad1) {
    __shared__ int hist[NB];
    __shared__ int base[NB];
    __shared__ float Wl[64 * 64];
    __shared__ float xs[16 * 64];
    int t = threadIdx.x;
    if (blockIdx.x < NPB) {
        // ---- partition body (R11-proven, verbatim logic) ----
        for (int i = t; i < NB; i += 256) hist[i] = 0;
        __syncthreads();
        int e0 = blockIdx.x * CH;
        int e1 = e0 + CH < EA ? e0 + CH : EA;
        for (int e = e0 + t; e < e1; e += 256) {
            int d = (e < E_EDGES) ? dst[e] : (e - E_EDGES);
            atomicAdd(&hist[d >> LG_BUCKET], 1);
        }
        __syncthreads();
        for (int i = t; i < NB; i += 256) {
            int h = hist[i];
            base[i] = h ? atomicAdd(&bcnt[i], h) : 0;
            hist[i] = 0;   // reuse as local cursor
        }
        __syncthreads();
        for (int e = e0 + t; e < e1; e += 256) {
            int s, d;
            if (e < E_EDGES) { s = src[e]; d = dst[e]; } else { s = e - E_EDGES; d = s; }
            int b = d >> LG_BUCKET;
            int r = base[b] + atomicAdd(&hist[b], 1);
            if (r < SLOTS)   // overflow guard (statistically impossible)
                edges[(b << LG_SLOTS) + r] = ((unsigned)(d & (BUCKET - 1)) << SRC_BITS) | (unsigned)s;
        }
    } else {
        // ---- lin1 body (R13-proven, verbatim logic) ----
        int r0 = (blockIdx.x - NPB) * 16;
        const float4* W4 = (const float4*)W1;
        float4* Wl4 = (float4*)Wl;
        #pragma unroll
        for (int i = 0; i < 4; i++) Wl4[t + i * 256] = W4[t + i * 256];
        ((float4*)xs)[t] = ((const float4*)(x + (size_t)r0 * 64))[t];
        __syncthreads();
        int c = t & 63, tg = t >> 6;
        float acc0 = 0.f, acc1 = 0.f, acc2 = 0.f, acc3 = 0.f;
        #pragma unroll
        for (int k = 0; k < 64; k++) {
            float w = Wl[k * 64 + c];
            acc0 += xs[(tg * 4 + 0) * 64 + k] * w;
            acc1 += xs[(tg * 4 + 1) * 64 + k] * w;
            acc2 += xs[(tg * 4 + 2) * 64 + k] * w;
            acc3 += xs[(tg * 4 + 3) * 64 + k] * w;
        }
        int r = r0 + tg * 4;
        h1[(size_t)(r + 0) * 64 + c] = (f16)acc0;
        h1[(size_t)(r + 1) * 64 + c] = (f16)acc1;
        h1[(size_t)(r + 2) * 64 + c] = (f16)acc2;
        h1[(size_t)(r + 3) * 64 + c] = (f16)acc3;
        float s_c = a1s[c], d_c = a1d[c];
        float vs0 = acc0 * s_c, vd0 = acc0 * d_c;
        float vs1 = acc1 * s_c, vd1 = acc1 * d_c;
        float vs2 = acc2 * s_c, vd2 = acc2 * d_c;
        float vs3 = acc3 * s_c, vd3 = acc3 * d_c;
        #pragma unroll
        for (int off = 16; off > 0; off >>= 1) {
            vs0 += __shfl_xor(vs0, off); vd0 += __shfl_xor(vd0, off);
            vs1 += __shfl_xor(vs1, off); vd1 += __shfl_xor(vd1, off);
            vs2 += __shfl_xor(vs2, off); vd2 += __shfl_xor(vd2, off);
            vs3 += __shfl_xor(vs3, off); vd3 += __shfl_xor(vd3, off);
        }
        if ((c & 31) == 0) {
            int h = c >> 5;
            as1[(r + 0) * 2 + h] = vs0; ad1[(r + 0) * 2 + h] = vd0;
            as1[(r + 1) * 2 + h] = vs1; ad1[(r + 1) * 2 + h] = vd1;
            as1[(r + 2) * 2 + h] = vs2; ad1[(r + 2) * 2 + h] = vd2;
            as1[(r + 3) * 2 + h] = vs3; ad1[(r + 3) * 2 + h] = vd3;
        }
    }
}

// per-bucket local scatter (in-place via LDS staging); emits rowSD = {start, deg}
__global__ __launch_bounds__(256) void bucket_scatter(unsigned* __restrict__ edges,
                                                      const int* __restrict__ bcnt,
                                                      int2* __restrict__ rowSD) {
    __shared__ unsigned stage[SLOTS];   // 32 KB
    __shared__ int hist[256];
    __shared__ int sc[256];
    int b = blockIdx.x;
    int t = threadIdx.x;
    int node0 = b << LG_BUCKET;
    int cnt = bcnt[b]; if (cnt > SLOTS) cnt = SLOTS;
    int baseg = b << LG_SLOTS;
    hist[t] = 0;
    __syncthreads();
    for (int i = t; i < cnt; i += 256) {
        unsigned p = edges[baseg + i];
        stage[i] = p;
        atomicAdd(&hist[p >> SRC_BITS], 1);
    }
    __syncthreads();
    int v = hist[t];
    sc[t] = v;
    __syncthreads();
    for (int off = 1; off < 256; off <<= 1) {
        int x = (t >= off) ? sc[t - off] : 0;
        __syncthreads();
        sc[t] += x;
        __syncthreads();
    }
    int excl = sc[t] - v;
    if (t < BUCKET && node0 + t < N_NODES) rowSD[node0 + t] = make_int2(baseg + excl, v);
    hist[t] = excl;   // reuse as cursor
    __syncthreads();
    for (int i = t; i < cnt; i += 256) {
        unsigned p = stage[i];
        int r = atomicAdd(&hist[p >> SRC_BITS], 1);
        edges[baseg + r] = p & SRC_MASK;   // in-place: now plain src index
    }
}

// ---------------- Layer 1 aggregation + fused layer-2 linear (eighth-wave) ----------------
// 8 lanes per node; lane l covers features 8l..8l+7 (one uint4 = 8 f16), head hh = l>>2.
// Single pass (R11/R14-proven scheme): per 8-edge chunk each lane computes its edge's p
// (both heads, cvt_pkrtz-packed); inner loop shfl-broadcasts s and p within the 8-lane
// group; head via v_perm splat; v_pk_fma_f16 accumulate. 8 nodes per wave.

__global__ __launch_bounds__(256) void agg1_kernel(
        const int2* __restrict__ rowSD, const int* __restrict__ srcs,
        const f16* __restrict__ h1, const float* __restrict__ as1,
        const float* __restrict__ ad1, const float* __restrict__ b1,
        const float* __restrict__ W2, const float* __restrict__ a2s,
        const float* __restrict__ a2d,
        f16* __restrict__ h2, float* __restrict__ as2, float* __restrict__ ad2) {
    __shared__ float rowb[32][68];
    __shared__ float W2l[64 * 32];
    int tid = threadIdx.x;
    for (int i = tid; i < 2048; i += 256) W2l[i] = W2[i];
    int owid = tid >> 3;        // 0..31 node slot in block
    int l = tid & 7;            // lane in eighth
    int hh = l >> 2;            // head for this lane's 8 features
    int v = blockIdx.x * 32 + owid;
    int2 sd = rowSD[v];
    int start = sd.x, deg = sd.y;
    float2 adv = ((const float2*)ad1)[v];
    const float2* as1v2 = (const float2*)as1;
    const uint4* h1q = (const uint4*)h1;   // row = 8 uint4 (64 f16)
    unsigned psel = hh ? 0x03020302u : 0x01000100u;   // splat hi16 : lo16
    half2v ax0 = {}, ax1 = {}, ax2 = {}, ax3 = {};
    half2v bx0 = {}, bx1 = {}, bx2 = {}, bx3 = {};
    float z0 = 0.f, z1 = 0.f;
    for (int c = 0; c < deg; c += 8) {
        int cnt = deg - c; if (cnt > 8) cnt = 8;
        int sreg = 0, pki = 0;
        if (c + l < deg) {
            sreg = srcs[start + c + l];
            float2 a = as1v2[sreg];
            half2v pk = cvtpk(__expf(leaky(a.x + adv.x)), __expf(leaky(a.y + adv.y)));
            z0 += (float)pk.x;   // z from rounded p: cancels RTZ bias
            z1 += (float)pk.y;
            pki = (int)h2u(pk);
        }
        int j = 0;
        for (; j + 1 < cnt; j += 2) {
            int s0 = __shfl(sreg, j, 8), s1 = __shfl(sreg, j + 1, 8);
            unsigned u0 = (unsigned)__shfl(pki, j, 8);
            unsigned u1 = (unsigned)__shfl(pki, j + 1, 8);
            uint4 g0 = h1q[(size_t)s0 * 8 + l];
            uint4 g1 = h1q[(size_t)s1 * 8 + l];
            half2v p0 = u2h(__builtin_amdgcn_perm(u0, u0, psel));
            half2v p1 = u2h(__builtin_amdgcn_perm(u1, u1, psel));
            ax0 += p0 * u2h(g0.x); ax1 += p0 * u2h(g0.y);
            ax2 += p0 * u2h(g0.z); ax3 += p0 * u2h(g0.w);
            bx0 += p1 * u2h(g1.x); bx1 += p1 * u2h(g1.y);
            bx2 += p1 * u2h(g1.z); bx3 += p1 * u2h(g1.w);
        }
        if (j < cnt) {
            int s0 = __shfl(sreg, j, 8);
            unsigned u0 = (unsigned)__shfl(pki, j, 8);
            uint4 g0 = h1q[(size_t)s0 * 8 + l];
            half2v p0 = u2h(__builtin_amdgcn_perm(u0, u0, psel));
            ax0 += p0 * u2h(g0.x); ax1 += p0 * u2h(g0.y);
            ax2 += p0 * u2h(g0.z); ax3 += p0 * u2h(g0.w);
        }
    }
    // z reduce across the 8-lane group
    #pragma unroll
    for (int off = 4; off > 0; off >>= 1) {
        z0 += __shfl_xor(z0, off);
        z1 += __shfl_xor(z1, off);
    }
    // epilogue: elu(out1) -> LDS row; fused lin2
    float rz = 1.f / (hh ? z1 : z0);
    half2v t0 = ax0 + bx0, t1 = ax1 + bx1, t2 = ax2 + bx2, t3 = ax3 + bx3;
    float4 ba = ((const float4*)b1)[2 * l];
    float4 bb = ((const float4*)b1)[2 * l + 1];
    float o0 = (float)t0.x * rz + ba.x;
    float o1 = (float)t0.y * rz + ba.y;
    float o2 = (float)t1.x * rz + ba.z;
    float o3 = (float)t1.y * rz + ba.w;
    float o4 = (float)t2.x * rz + bb.x;
    float o5 = (float)t2.y * rz + bb.y;
    float o6 = (float)t3.x * rz + bb.z;
    float o7 = (float)t3.y * rz + bb.w;
    o0 = o0 > 0.f ? o0 : __expf(o0) - 1.f;
    o1 = o1 > 0.f ? o1 : __expf(o1) - 1.f;
    o2 = o2 > 0.f ? o2 : __expf(o2) - 1.f;
    o3 = o3 > 0.f ? o3 : __expf(o3) - 1.f;
    o4 = o4 > 0.f ? o4 : __expf(o4) - 1.f;
    o5 = o5 > 0.f ? o5 : __expf(o5) - 1.f;
    o6 = o6 > 0.f ? o6 : __expf(o6) - 1.f;
    o7 = o7 > 0.f ? o7 : __expf(o7) - 1.f;
    rowb[owid][8 * l]     = o0;
    rowb[owid][8 * l + 1] = o1;
    rowb[owid][8 * l + 2] = o2;
    rowb[owid][8 * l + 3] = o3;
    rowb[owid][8 * l + 4] = o4;
    rowb[owid][8 * l + 5] = o5;
    rowb[owid][8 * l + 6] = o6;
    rowb[owid][8 * l + 7] = o7;
    __syncthreads();   // covers W2l staging (rowb is same-wave)
    // fused lin2: lane computes h2 columns 4l..4l+3
    float hc0 = 0.f, hc1 = 0.f, hc2 = 0.f, hc3 = 0.f;
    #pragma unroll 8
    for (int k = 0; k < 64; k++) {
        float r = rowb[owid][k];
        hc0 += r * W2l[k * 32 + 4 * l];
        hc1 += r * W2l[k * 32 + 4 * l + 1];
        hc2 += r * W2l[k * 32 + 4 * l + 2];
        hc3 += r * W2l[k * 32 + 4 * l + 3];
    }
    half2v hlo, hhi;
    hlo.x = (f16)hc0; hlo.y = (f16)hc1;   // RTN rounding (matches prior (f16) casts)
    hhi.x = (f16)hc2; hhi.y = (f16)hc3;
    uint2 hw; hw.x = h2u(hlo); hw.y = h2u(hhi);
    ((uint2*)h2)[(size_t)v * 8 + l] = hw;   // 8 B coalesced store
    float4 sa = ((const float4*)a2s)[l];
    float4 da = ((const float4*)a2d)[l];
    float vs = hc0 * sa.x + hc1 * sa.y + hc2 * sa.z + hc3 * sa.w;
    float vd = hc0 * da.x + hc1 * da.y + hc2 * da.z + hc3 * da.w;
    #pragma unroll
    for (int off = 4; off > 0; off >>= 1) { vs += __shfl_xor(vs, off); vd += __shfl_xor(vd, off); }
    if (l == 0) { as2[v] = vs; ad2[v] = vd; }
}

// ---------------- Layer 2: aggregation (R13-proven, verbatim) ----------------

__global__ __launch_bounds__(256) void agg2_kernel(
        const int2* __restrict__ rowSD, const int* __restrict__ srcs,
        const f16* __restrict__ h2, const float* __restrict__ as2,
        const float* __restrict__ ad2, const float* __restrict__ b2,
        float* __restrict__ out) {
    __shared__ float pbuf2[4][CAP];
    int wid = threadIdx.x >> 6;
    int v = blockIdx.x * 4 + wid;
    int lane = threadIdx.x & 63;
    int2 sd = rowSD[v];
    int start = sd.x, deg = sd.y;
    float adv = ad2[v];
    float z = 0.f;
    if (deg <= CAP) {
        for (int idx = lane; idx < deg; idx += 64) {
            int s = srcs[start + idx];
            float p = __expf(leaky(as2[s] + adv));
            pbuf2[wid][idx] = p;
            z += p;
        }
        #pragma unroll
        for (int off = 32; off > 0; off >>= 1) z += __shfl_xor(z, off);
        int q8 = lane >> 3, f8 = lane & 7;
        const uint2* h2q = (const uint2*)h2;   // row = 8 uint2 (32 f16)
        float a0 = 0.f, a1 = 0.f, a2 = 0.f, a3 = 0.f;
        int idx = q8;
        for (; idx + 8 < deg; idx += 16) {
            int s0 = srcs[start + idx];
            int s1 = srcs[start + idx + 8];
            float p0 = pbuf2[wid][idx];
            float p1 = pbuf2[wid][idx + 8];
            uint2 g0 = h2q[(size_t)s0 * 8 + f8];
            uint2 g1 = h2q[(size_t)s1 * 8 + f8];
            half2v l0 = u2h(g0.x), hi0 = u2h(g0.y);
            half2v l1 = u2h(g1.x), hi1 = u2h(g1.y);
            a0 += p0 * (float)l0.x  + p1 * (float)l1.x;
            a1 += p0 * (float)l0.y  + p1 * (float)l1.y;
            a2 += p0 * (float)hi0.x + p1 * (float)hi1.x;
            a3 += p0 * (float)hi0.y + p1 * (float)hi1.y;
        }
        if (idx < deg) {
            int s0 = srcs[start + idx];
            float p0 = pbuf2[wid][idx];
            uint2 g0 = h2q[(size_t)s0 * 8 + f8];
            half2v l0 = u2h(g0.x), hi0 = u2h(g0.y);
            a0 += p0 * (float)l0.x;
            a1 += p0 * (float)l0.y;
            a2 += p0 * (float)hi0.x;
            a3 += p0 * (float)hi0.y;
        }
        #pragma unroll
        for (int off = 8; off < 64; off <<= 1) {
            a0 += __shfl_xor(a0, off);
            a1 += __shfl_xor(a1, off);
            a2 += __shfl_xor(a2, off);
            a3 += __shfl_xor(a3, off);
        }
        if (lane < 8) {
            float rz = 1.f / z;
            float4 r;
            r.x = a0 * rz + b2[4 * f8];
            r.y = a1 * rz + b2[4 * f8 + 1];
            r.z = a2 * rz + b2[4 * f8 + 2];
            r.w = a3 * rz + b2[4 * f8 + 3];
            ((float4*)out)[(size_t)v * 8 + f8] = r;
        }
    } else {
        int q = lane >> 4, f = lane & 15;
        const half2v* h2v = (const half2v*)h2;
        float a0 = 0.f, a1 = 0.f;
        float m = -1e30f;
        for (int idx = lane; idx < deg; idx += 64)
            m = fmaxf(m, leaky(as2[srcs[start + idx]] + adv));
        #pragma unroll
        for (int off = 32; off > 0; off >>= 1) m = fmaxf(m, __shfl_xor(m, off));
        for (int idx = lane; idx < deg; idx += 64)
            z += __expf(leaky(as2[srcs[start + idx]] + adv) - m);
        #pragma unroll
        for (int off = 32; off > 0; off >>= 1) z += __shfl_xor(z, off);
        for (int idx = q; idx < deg; idx += 4) {
            int s0 = srcs[start + idx];
            float p0 = __expf(leaky(as2[s0] + adv) - m);
            half2v g0 = h2v[(size_t)s0 * 16 + f];
            a0 += p0 * (float)g0.x; a1 += p0 * (float)g0.y;
        }
        a0 += __shfl_xor(a0, 16); a1 += __shfl_xor(a1, 16);
        a0 += __shfl_xor(a0, 32); a1 += __shfl_xor(a1, 32);
        if (lane < 16) {
            float rz = 1.f / z;
            float2 r;
            r.x = a0 * rz + b2[2 * f];
            r.y = a1 * rz + b2[2 * f + 1];
            ((float2*)out)[(size_t)v * 16 + f] = r;
        }
    }
}

// ---------------- launch ----------------

extern "C" void kernel_launch(void* const* d_in, const int* in_sizes, int n_in,
                              void* d_out, int out_size, void* d_ws, size_t ws_size,
                              hipStream_t stream) {
    const float* x    = (const float*)d_in[0];
    const int*   ei   = (const int*)d_in[1];
    const float* W1   = (const float*)d_in[2];
    const float* a1s  = (const float*)d_in[3];
    const float* a1d  = (const float*)d_in[4];
    const float* b1   = (const float*)d_in[5];
    const float* W2   = (const float*)d_in[6];
    const float* a2s  = (const float*)d_in[7];
    const float* a2d  = (const float*)d_in[8];
    const float* b2   = (const float*)d_in[9];
    const int* src = ei;
    const int* dst = ei + E_EDGES;
    float* out = (float*)d_out;

    // workspace layout (4-byte words, 64-word aligned regions) — total ~35.2 MB (proven)
    size_t o = 0;
    int2* rowSD     = (int2*)((int*)d_ws + o);     o += ((2 * N_NODES + 63) / 64) * 64;
    int* bcnt       = (int*)d_ws + o;              o += ((NB + 63) / 64) * 64;
    unsigned* edges = (unsigned*)((int*)d_ws + o); o += (size_t)NB * SLOTS;   // packed, then in-place srcs
    f16* h1         = (f16*)((int*)d_ws + o);      o += (size_t)N_NODES * 32;   // N x 64 f16
    f16* h2         = (f16*)((int*)d_ws + o);      o += (size_t)N_NODES * 16;   // N x 32 f16
    float* as1      = (float*)d_ws + o;            o += (size_t)N_NODES * 2;
    float* ad1      = (float*)d_ws + o;            o += (size_t)N_NODES * 2;
    float* as2      = (float*)d_ws + o;            o += (size_t)N_NODES;
    float* ad2      = (float*)d_ws + o;            o += (size_t)N_NODES;
    const int* srcs = (const int*)edges;

    // CSR build + lin1 (fused: partition blocks first, lin1 blocks fill the rest)
    (void)hipMemsetAsync(bcnt, 0, NB * sizeof(int), stream);
    part_lin1_kernel<<<NPB + NLIN1, 256, 0, stream>>>(src, dst, bcnt, edges,
                                                      x, W1, a1s, a1d, h1, as1, ad1);
    bucket_scatter<<<NB, 256, 0, stream>>>(edges, bcnt, rowSD);

    // layer 1 aggregation + fused layer 2 linear (eighth-wave: 32 nodes/block)
    agg1_kernel<<<N_NODES / 32, 256, 0, stream>>>(rowSD, srcs, h1, as1, ad1, b1,
                                                  W2, a2s, a2d, h2, as2, ad2);
    // layer 2 aggregation
    agg2_kernel<<<N_NODES / 4, 256, 0, stream>>>(rowSD, srcs, h2, as2, ad2, b2, out);
}

// Round 16
// 140.357 us; speedup vs baseline: 1.4926x; 1.0948x over previous
//
#include <hip/hip_runtime.h>
#include <math.h>

#define N_NODES 100000
#define E_EDGES 1600000
#define EA (E_EDGES + N_NODES)   // with self loops
#define NEG_SLOPE 0.2f
#define LG_BUCKET 8
#define BUCKET (1 << LG_BUCKET)            // 256-node dst buckets (R11-proven)
#define NB ((N_NODES + BUCKET - 1) >> LG_BUCKET)   // 391
#define LG_SLOTS 13
#define SLOTS (1 << LG_SLOTS)    // per-bucket slack region (mean fill ~4350)
#define CH 8192                  // edges per block in partition pass (R11-proven)
#define NPB ((EA + CH - 1) / CH) // 208
#define NLIN1 (N_NODES / 16)     // lin1 blocks (fused behind partition)
#define SRC_BITS 17
#define SRC_MASK ((1u << SRC_BITS) - 1)

typedef _Float16 f16;
typedef _Float16 half2v __attribute__((ext_vector_type(2)));

__device__ __forceinline__ float leaky(float e) { return e >= 0.f ? e : NEG_SLOPE * e; }
__device__ __forceinline__ unsigned h2u(half2v h) { return __builtin_bit_cast(unsigned, h); }
__device__ __forceinline__ half2v u2h(unsigned u) { return __builtin_bit_cast(half2v, u); }
__device__ __forceinline__ half2v cvtpk(float a, float b) {
    return __builtin_bit_cast(half2v, __builtin_amdgcn_cvt_pkrtz(a, b));
}

// ---------------- Fat kernel: CSR partition (blocks 0..NPB-1) + lin1 (rest) ----------------
// (R15-proven: back-solved budget shows fusion saves ~12 us vs serial launches)

__global__ __launch_bounds__(256) void part_lin1_kernel(
        const int* __restrict__ src, const int* __restrict__ dst,
        int* __restrict__ bcnt, unsigned* __restrict__ edges,
        const float* __restrict__ x, const float* __restrict__ W1,
        const float* __restrict__ a1s, const float* __restrict__ a1d,
        f16* __restrict__ h1, float* __restrict__ as1, float* __restrict__ ad1) {
    __shared__ int hist[NB];
    __shared__ int base[NB];
    __shared__ float Wl[64 * 64];
    __shared__ float xs[16 * 64];
    int t = threadIdx.x;
    if (blockIdx.x < NPB) {
        // ---- partition body (R11-proven, verbatim logic) ----
        for (int i = t; i < NB; i += 256) hist[i] = 0;
        __syncthreads();
        int e0 = blockIdx.x * CH;
        int e1 = e0 + CH < EA ? e0 + CH : EA;
        for (int e = e0 + t; e < e1; e += 256) {
            int d = (e < E_EDGES) ? dst[e] : (e - E_EDGES);
            atomicAdd(&hist[d >> LG_BUCKET], 1);
        }
        __syncthreads();
        for (int i = t; i < NB; i += 256) {
            int h = hist[i];
            base[i] = h ? atomicAdd(&bcnt[i], h) : 0;
            hist[i] = 0;   // reuse as local cursor
        }
        __syncthreads();
        for (int e = e0 + t; e < e1; e += 256) {
            int s, d;
            if (e < E_EDGES) { s = src[e]; d = dst[e]; } else { s = e - E_EDGES; d = s; }
            int b = d >> LG_BUCKET;
            int r = base[b] + atomicAdd(&hist[b], 1);
            if (r < SLOTS)   // overflow guard (statistically impossible)
                edges[(b << LG_SLOTS) + r] = ((unsigned)(d & (BUCKET - 1)) << SRC_BITS) | (unsigned)s;
        }
    } else {
        // ---- lin1 body (R13-proven, verbatim logic) ----
        int r0 = (blockIdx.x - NPB) * 16;
        const float4* W4 = (const float4*)W1;
        float4* Wl4 = (float4*)Wl;
        #pragma unroll
        for (int i = 0; i < 4; i++) Wl4[t + i * 256] = W4[t + i * 256];
        ((float4*)xs)[t] = ((const float4*)(x + (size_t)r0 * 64))[t];
        __syncthreads();
        int c = t & 63, tg = t >> 6;
        float acc0 = 0.f, acc1 = 0.f, acc2 = 0.f, acc3 = 0.f;
        #pragma unroll
        for (int k = 0; k < 64; k++) {
            float w = Wl[k * 64 + c];
            acc0 += xs[(tg * 4 + 0) * 64 + k] * w;
            acc1 += xs[(tg * 4 + 1) * 64 + k] * w;
            acc2 += xs[(tg * 4 + 2) * 64 + k] * w;
            acc3 += xs[(tg * 4 + 3) * 64 + k] * w;
        }
        int r = r0 + tg * 4;
        h1[(size_t)(r + 0) * 64 + c] = (f16)acc0;
        h1[(size_t)(r + 1) * 64 + c] = (f16)acc1;
        h1[(size_t)(r + 2) * 64 + c] = (f16)acc2;
        h1[(size_t)(r + 3) * 64 + c] = (f16)acc3;
        float s_c = a1s[c], d_c = a1d[c];
        float vs0 = acc0 * s_c, vd0 = acc0 * d_c;
        float vs1 = acc1 * s_c, vd1 = acc1 * d_c;
        float vs2 = acc2 * s_c, vd2 = acc2 * d_c;
        float vs3 = acc3 * s_c, vd3 = acc3 * d_c;
        #pragma unroll
        for (int off = 16; off > 0; off >>= 1) {
            vs0 += __shfl_xor(vs0, off); vd0 += __shfl_xor(vd0, off);
            vs1 += __shfl_xor(vs1, off); vd1 += __shfl_xor(vd1, off);
            vs2 += __shfl_xor(vs2, off); vd2 += __shfl_xor(vd2, off);
            vs3 += __shfl_xor(vs3, off); vd3 += __shfl_xor(vd3, off);
        }
        if ((c & 31) == 0) {
            int h = c >> 5;
            as1[(r + 0) * 2 + h] = vs0; ad1[(r + 0) * 2 + h] = vd0;
            as1[(r + 1) * 2 + h] = vs1; ad1[(r + 1) * 2 + h] = vd1;
            as1[(r + 2) * 2 + h] = vs2; ad1[(r + 2) * 2 + h] = vd2;
            as1[(r + 3) * 2 + h] = vs3; ad1[(r + 3) * 2 + h] = vd3;
        }
    }
}

// per-bucket local scatter (in-place via LDS staging); emits rowSD = {start, deg}
__global__ __launch_bounds__(256) void bucket_scatter(unsigned* __restrict__ edges,
                                                      const int* __restrict__ bcnt,
                                                      int2* __restrict__ rowSD) {
    __shared__ unsigned stage[SLOTS];   // 32 KB
    __shared__ int hist[256];
    __shared__ int sc[256];
    int b = blockIdx.x;
    int t = threadIdx.x;
    int node0 = b << LG_BUCKET;
    int cnt = bcnt[b]; if (cnt > SLOTS) cnt = SLOTS;
    int baseg = b << LG_SLOTS;
    hist[t] = 0;
    __syncthreads();
    for (int i = t; i < cnt; i += 256) {
        unsigned p = edges[baseg + i];
        stage[i] = p;
        atomicAdd(&hist[p >> SRC_BITS], 1);
    }
    __syncthreads();
    int v = hist[t];
    sc[t] = v;
    __syncthreads();
    for (int off = 1; off < 256; off <<= 1) {
        int x = (t >= off) ? sc[t - off] : 0;
        __syncthreads();
        sc[t] += x;
        __syncthreads();
    }
    int excl = sc[t] - v;
    if (t < BUCKET && node0 + t < N_NODES) rowSD[node0 + t] = make_int2(baseg + excl, v);
    hist[t] = excl;   // reuse as cursor
    __syncthreads();
    for (int i = t; i < cnt; i += 256) {
        unsigned p = stage[i];
        int r = atomicAdd(&hist[p >> SRC_BITS], 1);
        edges[baseg + r] = p & SRC_MASK;   // in-place: now plain src index
    }
}

// ---------------- Layer 1 aggregation + fused layer-2 linear (R15-proven, verbatim) ----------------
// 8 lanes per node; lane l covers features 8l..8l+7 (one uint4 = 8 f16), head hh = l>>2.

__global__ __launch_bounds__(256) void agg1_kernel(
        const int2* __restrict__ rowSD, const int* __restrict__ srcs,
        const f16* __restrict__ h1, const float* __restrict__ as1,
        const float* __restrict__ ad1, const float* __restrict__ b1,
        const float* __restrict__ W2, const float* __restrict__ a2s,
        const float* __restrict__ a2d,
        f16* __restrict__ h2, float* __restrict__ as2, float* __restrict__ ad2) {
    __shared__ float rowb[32][68];
    __shared__ float W2l[64 * 32];
    int tid = threadIdx.x;
    for (int i = tid; i < 2048; i += 256) W2l[i] = W2[i];
    int owid = tid >> 3;        // 0..31 node slot in block
    int l = tid & 7;            // lane in eighth
    int hh = l >> 2;            // head for this lane's 8 features
    int v = blockIdx.x * 32 + owid;
    int2 sd = rowSD[v];
    int start = sd.x, deg = sd.y;
    float2 adv = ((const float2*)ad1)[v];
    const float2* as1v2 = (const float2*)as1;
    const uint4* h1q = (const uint4*)h1;   // row = 8 uint4 (64 f16)
    unsigned psel = hh ? 0x03020302u : 0x01000100u;   // splat hi16 : lo16
    half2v ax0 = {}, ax1 = {}, ax2 = {}, ax3 = {};
    half2v bx0 = {}, bx1 = {}, bx2 = {}, bx3 = {};
    float z0 = 0.f, z1 = 0.f;
    for (int c = 0; c < deg; c += 8) {
        int cnt = deg - c; if (cnt > 8) cnt = 8;
        int sreg = 0, pki = 0;
        if (c + l < deg) {
            sreg = srcs[start + c + l];
            float2 a = as1v2[sreg];
            half2v pk = cvtpk(__expf(leaky(a.x + adv.x)), __expf(leaky(a.y + adv.y)));
            z0 += (float)pk.x;   // z from rounded p: cancels RTZ bias
            z1 += (float)pk.y;
            pki = (int)h2u(pk);
        }
        int j = 0;
        for (; j + 1 < cnt; j += 2) {
            int s0 = __shfl(sreg, j, 8), s1 = __shfl(sreg, j + 1, 8);
            unsigned u0 = (unsigned)__shfl(pki, j, 8);
            unsigned u1 = (unsigned)__shfl(pki, j + 1, 8);
            uint4 g0 = h1q[(size_t)s0 * 8 + l];
            uint4 g1 = h1q[(size_t)s1 * 8 + l];
            half2v p0 = u2h(__builtin_amdgcn_perm(u0, u0, psel));
            half2v p1 = u2h(__builtin_amdgcn_perm(u1, u1, psel));
            ax0 += p0 * u2h(g0.x); ax1 += p0 * u2h(g0.y);
            ax2 += p0 * u2h(g0.z); ax3 += p0 * u2h(g0.w);
            bx0 += p1 * u2h(g1.x); bx1 += p1 * u2h(g1.y);
            bx2 += p1 * u2h(g1.z); bx3 += p1 * u2h(g1.w);
        }
        if (j < cnt) {
            int s0 = __shfl(sreg, j, 8);
            unsigned u0 = (unsigned)__shfl(pki, j, 8);
            uint4 g0 = h1q[(size_t)s0 * 8 + l];
            half2v p0 = u2h(__builtin_amdgcn_perm(u0, u0, psel));
            ax0 += p0 * u2h(g0.x); ax1 += p0 * u2h(g0.y);
            ax2 += p0 * u2h(g0.z); ax3 += p0 * u2h(g0.w);
        }
    }
    // z reduce across the 8-lane group
    #pragma unroll
    for (int off = 4; off > 0; off >>= 1) {
        z0 += __shfl_xor(z0, off);
        z1 += __shfl_xor(z1, off);
    }
    // epilogue: elu(out1) -> LDS row; fused lin2
    float rz = 1.f / (hh ? z1 : z0);
    half2v t0 = ax0 + bx0, t1 = ax1 + bx1, t2 = ax2 + bx2, t3 = ax3 + bx3;
    float4 ba = ((const float4*)b1)[2 * l];
    float4 bb = ((const float4*)b1)[2 * l + 1];
    float o0 = (float)t0.x * rz + ba.x;
    float o1 = (float)t0.y * rz + ba.y;
    float o2 = (float)t1.x * rz + ba.z;
    float o3 = (float)t1.y * rz + ba.w;
    float o4 = (float)t2.x * rz + bb.x;
    float o5 = (float)t2.y * rz + bb.y;
    float o6 = (float)t3.x * rz + bb.z;
    float o7 = (float)t3.y * rz + bb.w;
    o0 = o0 > 0.f ? o0 : __expf(o0) - 1.f;
    o1 = o1 > 0.f ? o1 : __expf(o1) - 1.f;
    o2 = o2 > 0.f ? o2 : __expf(o2) - 1.f;
    o3 = o3 > 0.f ? o3 : __expf(o3) - 1.f;
    o4 = o4 > 0.f ? o4 : __expf(o4) - 1.f;
    o5 = o5 > 0.f ? o5 : __expf(o5) - 1.f;
    o6 = o6 > 0.f ? o6 : __expf(o6) - 1.f;
    o7 = o7 > 0.f ? o7 : __expf(o7) - 1.f;
    rowb[owid][8 * l]     = o0;
    rowb[owid][8 * l + 1] = o1;
    rowb[owid][8 * l + 2] = o2;
    rowb[owid][8 * l + 3] = o3;
    rowb[owid][8 * l + 4] = o4;
    rowb[owid][8 * l + 5] = o5;
    rowb[owid][8 * l + 6] = o6;
    rowb[owid][8 * l + 7] = o7;
    __syncthreads();   // covers W2l staging (rowb is same-wave)
    // fused lin2: lane computes h2 columns 4l..4l+3
    float hc0 = 0.f, hc1 = 0.f, hc2 = 0.f, hc3 = 0.f;
    #pragma unroll 8
    for (int k = 0; k < 64; k++) {
        float r = rowb[owid][k];
        hc0 += r * W2l[k * 32 + 4 * l];
        hc1 += r * W2l[k * 32 + 4 * l + 1];
        hc2 += r * W2l[k * 32 + 4 * l + 2];
        hc3 += r * W2l[k * 32 + 4 * l + 3];
    }
    half2v hlo, hhi;
    hlo.x = (f16)hc0; hlo.y = (f16)hc1;   // RTN rounding (matches prior (f16) casts)
    hhi.x = (f16)hc2; hhi.y = (f16)hc3;
    uint2 hw; hw.x = h2u(hlo); hw.y = h2u(hhi);
    ((uint2*)h2)[(size_t)v * 8 + l] = hw;   // 8 B coalesced store
    float4 sa = ((const float4*)a2s)[l];
    float4 da = ((const float4*)a2d)[l];
    float vs = hc0 * sa.x + hc1 * sa.y + hc2 * sa.z + hc3 * sa.w;
    float vd = hc0 * da.x + hc1 * da.y + hc2 * da.z + hc3 * da.w;
    #pragma unroll
    for (int off = 4; off > 0; off >>= 1) { vs += __shfl_xor(vs, off); vd += __shfl_xor(vd, off); }
    if (l == 0) { as2[v] = vs; ad2[v] = vd; }
}

// ---------------- Layer 2: aggregation (4 lanes/node, single-pass, agg1-template) ----------------
// Lane l of a 4-lane group covers features 8l..8l+7 (one uint4); 16 nodes/wave.
// Per 4-edge chunk each lane computes its edge's p (cvtpk(p,p): both halves = p);
// inner loop shfl-broadcasts s,p within the width-4 group; v_pk_fma_f16 accumulate.

__global__ __launch_bounds__(256) void agg2_kernel(
        const int2* __restrict__ rowSD, const int* __restrict__ srcs,
        const f16* __restrict__ h2, const float* __restrict__ as2,
        const float* __restrict__ ad2, const float* __restrict__ b2,
        float* __restrict__ out) {
    int tid = threadIdx.x;
    int owid = tid >> 2;        // 0..63 node slot in block
    int l = tid & 3;            // lane in group of 4
    int v = blockIdx.x * 64 + owid;
    if (v >= N_NODES) return;   // tail guard (no barriers in this kernel)
    int2 sd = rowSD[v];
    int start = sd.x, deg = sd.y;
    float adv = ad2[v];
    const uint4* h2q = (const uint4*)h2;   // row = 4 uint4 (32 f16)
    half2v ax0 = {}, ax1 = {}, ax2 = {}, ax3 = {};
    half2v bx0 = {}, bx1 = {}, bx2 = {}, bx3 = {};
    float z = 0.f;
    for (int c = 0; c < deg; c += 4) {
        int cnt = deg - c; if (cnt > 4) cnt = 4;
        int sreg = 0, pki = 0;
        if (c + l < deg) {
            sreg = srcs[start + c + l];
            float p = __expf(leaky(as2[sreg] + adv));
            half2v pk = cvtpk(p, p);
            z += (float)pk.x;   // z from rounded p: cancels RTZ bias
            pki = (int)h2u(pk);
        }
        int j = 0;
        for (; j + 1 < cnt; j += 2) {
            int s0 = __shfl(sreg, j, 4), s1 = __shfl(sreg, j + 1, 4);
            unsigned u0 = (unsigned)__shfl(pki, j, 4);
            unsigned u1 = (unsigned)__shfl(pki, j + 1, 4);
            uint4 g0 = h2q[(size_t)s0 * 4 + l];
            uint4 g1 = h2q[(size_t)s1 * 4 + l];
            half2v p0 = u2h(u0), p1 = u2h(u1);
            ax0 += p0 * u2h(g0.x); ax1 += p0 * u2h(g0.y);
            ax2 += p0 * u2h(g0.z); ax3 += p0 * u2h(g0.w);
            bx0 += p1 * u2h(g1.x); bx1 += p1 * u2h(g1.y);
            bx2 += p1 * u2h(g1.z); bx3 += p1 * u2h(g1.w);
        }
        if (j < cnt) {
            int s0 = __shfl(sreg, j, 4);
            unsigned u0 = (unsigned)__shfl(pki, j, 4);
            uint4 g0 = h2q[(size_t)s0 * 4 + l];
            half2v p0 = u2h(u0);
            ax0 += p0 * u2h(g0.x); ax1 += p0 * u2h(g0.y);
            ax2 += p0 * u2h(g0.z); ax3 += p0 * u2h(g0.w);
        }
    }
    // z reduce across the 4-lane group (aligned -> default-width xor stays in group)
    z += __shfl_xor(z, 2);
    z += __shfl_xor(z, 1);
    float rz = 1.f / z;
    half2v t0 = ax0 + bx0, t1 = ax1 + bx1, t2 = ax2 + bx2, t3 = ax3 + bx3;
    float4 b2a = ((const float4*)b2)[2 * l];
    float4 b2b = ((const float4*)b2)[2 * l + 1];
    float4 r0, r1;
    r0.x = (float)t0.x * rz + b2a.x;
    r0.y = (float)t0.y * rz + b2a.y;
    r0.z = (float)t1.x * rz + b2a.z;
    r0.w = (float)t1.y * rz + b2a.w;
    r1.x = (float)t2.x * rz + b2b.x;
    r1.y = (float)t2.y * rz + b2b.y;
    r1.z = (float)t3.x * rz + b2b.z;
    r1.w = (float)t3.y * rz + b2b.w;
    ((float4*)out)[(size_t)v * 8 + 2 * l]     = r0;
    ((float4*)out)[(size_t)v * 8 + 2 * l + 1] = r1;
}

// ---------------- launch ----------------

extern "C" void kernel_launch(void* const* d_in, const int* in_sizes, int n_in,
                              void* d_out, int out_size, void* d_ws, size_t ws_size,
                              hipStream_t stream) {
    const float* x    = (const float*)d_in[0];
    const int*   ei   = (const int*)d_in[1];
    const float* W1   = (const float*)d_in[2];
    const float* a1s  = (const float*)d_in[3];
    const float* a1d  = (const float*)d_in[4];
    const float* b1   = (const float*)d_in[5];
    const float* W2   = (const float*)d_in[6];
    const float* a2s  = (const float*)d_in[7];
    const float* a2d  = (const float*)d_in[8];
    const float* b2   = (const float*)d_in[9];
    const int* src = ei;
    const int* dst = ei + E_EDGES;
    float* out = (float*)d_out;

    // workspace layout (4-byte words, 64-word aligned regions) — total ~35.2 MB (proven)
    size_t o = 0;
    int2* rowSD     = (int2*)((int*)d_ws + o);     o += ((2 * N_NODES + 63) / 64) * 64;
    int* bcnt       = (int*)d_ws + o;              o += ((NB + 63) / 64) * 64;
    unsigned* edges = (unsigned*)((int*)d_ws + o); o += (size_t)NB * SLOTS;   // packed, then in-place srcs
    f16* h1         = (f16*)((int*)d_ws + o);      o += (size_t)N_NODES * 32;   // N x 64 f16
    f16* h2         = (f16*)((int*)d_ws + o);      o += (size_t)N_NODES * 16;   // N x 32 f16
    float* as1      = (float*)d_ws + o;            o += (size_t)N_NODES * 2;
    float* ad1      = (float*)d_ws + o;            o += (size_t)N_NODES * 2;
    float* as2      = (float*)d_ws + o;            o += (size_t)N_NODES;
    float* ad2      = (float*)d_ws + o;            o += (size_t)N_NODES;
    const int* srcs = (const int*)edges;

    // CSR build + lin1 (fused: partition blocks first, lin1 blocks fill the rest)
    (void)hipMemsetAsync(bcnt, 0, NB * sizeof(int), stream);
    part_lin1_kernel<<<NPB + NLIN1, 256, 0, stream>>>(src, dst, bcnt, edges,
                                                      x, W1, a1s, a1d, h1, as1, ad1);
    bucket_scatter<<<NB, 256, 0, stream>>>(edges, bcnt, rowSD);

    // layer 1 aggregation + fused layer 2 linear (eighth-wave: 32 nodes/block)
    agg1_kernel<<<N_NODES / 32, 256, 0, stream>>>(rowSD, srcs, h1, as1, ad1, b1,
                                                  W2, a2s, a2d, h2, as2, ad2);
    // layer 2 aggregation (4 lanes/node: 64 nodes/block, tail-guarded)
    agg2_kernel<<<(N_NODES + 63) / 64, 256, 0, stream>>>(rowSD, srcs, h2, as2, ad2, b2, out);
}